// Round 8
// baseline (180.149 us; speedup 1.0000x reference)
//
#include <hip/hip_runtime.h>
#include <math.h>

// M=512, N=1024, G=16, D=64, C=1024. All GEMM-shaped work on bf16 MFMA 16x16x32.
// pos_bias uses a bf16 hi/lo (Dekker) split MFMA (rounds 4/6: plain bf16 dot
// error ~2e-4 sign-flips entries in log-clip floor rows -> absmax 0.205).
//
// Round 8: attn_body drops LDS staging of B entirely — both MFMA operands use
// the A-layout X[lane&15][quad*8+j], which is a direct 16B global load from
// k/vt (both L2-resident, ~3 MB). Barriers per block: 64+4 -> 5. gemm_tile
// gets distance-2 register prefetch (one chunk-time < global latency).
//
// Pipeline (4 launches):
//   conv5    : fp32->bf16 casts
//   pos_bias : trig -> hi/lo LDS -> 6x MFMA -> log -> fp16 bias planes
//   projvt   : z=0: qk = [feat;ctx] @ [w_fc]^T + b ; z=1: vt = w_conv @ [feat;ctx]^T
//   attn_out : scores (direct-B MFMA) + fp16 bias -> softmax (regs) ->
//              bf16 weights in LDS -> out-GEMM vs vt (direct-B) -> d_out
//
// Workspace (float offsets), total 12,320,768 floats = 49.3 MB:
//   [0,1572864)        : shorts: in_bf (feat 524288 + ctx 1048576), qk_bf (1572864)
//   [1572864,5767168)  : bias_gt  fp16 (16,512,1024)
//   [5767168,9961472)  : bias_ctx fp16 (16,1024,512)
//   [9961472,10485760) : wconv_bf (1048576 s)
//   [10485760,11272192): vt_bf (G,64,1536) shorts; cols 0..511 feat, 512..1535 ctx
//   [11272192,12320768): wfcgt_bf + wfcctx_bf

typedef __attribute__((ext_vector_type(8))) short short8;   // 8 bf16 = 4 VGPRs
typedef __attribute__((ext_vector_type(4))) float floatx4;
typedef __attribute__((ext_vector_type(4))) _Float16 half4;

__device__ inline unsigned short f32_bf16_rne(float x) {
    union { float f; unsigned u; } v; v.f = x;
    unsigned u = v.u;
    return (unsigned short)((u + 0x7fffu + ((u >> 16) & 1u)) >> 16);
}

__device__ inline float bf16_f32(unsigned short h) {
    union { unsigned u; float f; } v; v.u = (unsigned)h << 16;
    return v.f;
}

__device__ __forceinline__ floatx4 mfma16(short8 a, short8 b, floatx4 c) {
    return __builtin_amdgcn_mfma_f32_16x16x32_bf16(a, b, c, 0, 0, 0);
}

// ---------------------------------------------------------------------------
// 64x64 tile NT bf16 GEMM core. 4 waves, 32x32 quadrant each, BK=64 with
// distance-2 register prefetch. Writes bf16. K%128==0, lda/ldb%8==0.
// ---------------------------------------------------------------------------
__device__ __forceinline__ void gemm_tile_bf16(
    const unsigned short* __restrict__ Ab, int lda,
    const unsigned short* __restrict__ Bb, int ldb, int K,
    unsigned short* __restrict__ Cb, int ldc,
    const float* __restrict__ biasvec,
    unsigned short* As, unsigned short* Bs)
{
    const int tid = threadIdx.x;
    const int lr = tid >> 2;
    const int lk = (tid & 3) * 8;
    const int lane = tid & 63;
    const int wave = tid >> 6;
    const int qr = (wave >> 1) * 32;
    const int qc = (wave & 1) * 32;
    const int m = lane & 15;
    const int quad = lane >> 4;

    const unsigned short* Ap = Ab + (long long)lr * lda + lk;
    const unsigned short* Bp = Bb + (long long)lr * ldb + lk;
    unsigned short* AsW = As + lr * 72 + lk;
    unsigned short* BsW = Bs + lr * 72 + lk;
    const unsigned short* a0p = As + (qr + m) * 72 + quad * 8;
    const unsigned short* b0p = Bs + (qc + m) * 72 + quad * 8;

    floatx4 acc00 = {0.f,0.f,0.f,0.f}, acc01 = {0.f,0.f,0.f,0.f};
    floatx4 acc10 = {0.f,0.f,0.f,0.f}, acc11 = {0.f,0.f,0.f,0.f};

    // distance-2 pipeline: p* = chunk to store this iter, q* = chunk after
    int4 pa0 = *(const int4*)Ap;
    int4 pa1 = *(const int4*)(Ap + 32);
    int4 pb0 = *(const int4*)Bp;
    int4 pb1 = *(const int4*)(Bp + 32);
    int4 qa0 = *(const int4*)(Ap + 64);
    int4 qa1 = *(const int4*)(Ap + 96);
    int4 qb0 = *(const int4*)(Bp + 64);
    int4 qb1 = *(const int4*)(Bp + 96);

    for (int k0 = 0; ; ) {
        __syncthreads();
        *(int4*)AsW        = pa0;
        *(int4*)(AsW + 32) = pa1;
        *(int4*)BsW        = pb0;
        *(int4*)(BsW + 32) = pb1;
        __syncthreads();
        pa0 = qa0; pa1 = qa1; pb0 = qb0; pb1 = qb1;
        const int kf = k0 + 128;
        if (kf < K) {            // prefetch two chunks ahead
            qa0 = *(const int4*)(Ap + kf);
            qa1 = *(const int4*)(Ap + kf + 32);
            qb0 = *(const int4*)(Bp + kf);
            qb1 = *(const int4*)(Bp + kf + 32);
        }
        #pragma unroll
        for (int kk = 0; kk < 64; kk += 32) {
            short8 a0 = *(const short8*)(a0p + kk);
            short8 a1 = *(const short8*)(a0p + 16 * 72 + kk);
            short8 b0 = *(const short8*)(b0p + kk);
            short8 b1 = *(const short8*)(b0p + 16 * 72 + kk);
            acc00 = mfma16(a0, b0, acc00);
            acc01 = mfma16(a0, b1, acc01);
            acc10 = mfma16(a1, b0, acc10);
            acc11 = mfma16(a1, b1, acc11);
        }
        k0 += 64;
        if (k0 >= K) break;
    }

    float bias0 = 0.f, bias1 = 0.f;
    if (biasvec) { bias0 = biasvec[qc + m]; bias1 = biasvec[qc + 16 + m]; }

    const floatx4 accs[2][2] = { {acc00, acc01}, {acc10, acc11} };
    #pragma unroll
    for (int i = 0; i < 2; ++i)
        #pragma unroll
        for (int r = 0; r < 4; ++r) {
            const int lrow = qr + i * 16 + quad * 4 + r;
            #pragma unroll
            for (int j = 0; j < 2; ++j) {
                const int lcol = qc + j * 16 + m;
                float val = accs[i][j][r] + (j ? bias1 : bias0);
                Cb[(long long)lrow * ldc + lcol] = f32_bf16_rne(val);
            }
        }
}

// ---------------------------------------------------------------------------
// Merged proj + vt. z=0: qk rows 0..1535 = [feat;ctx] @ w_fc^T + b (w per half).
// z=1: vt[g][o][c] = w_conv[g][o] . in[c], c over 1536 concat rows.
// ---------------------------------------------------------------------------
__global__ __launch_bounds__(256) void projvt_kernel(
    const unsigned short* __restrict__ in_bf, const unsigned short* __restrict__ wgt,
    const unsigned short* __restrict__ wctx,
    const float* __restrict__ bgt, const float* __restrict__ bctx,
    unsigned short* __restrict__ qk,
    const unsigned short* __restrict__ wconv, unsigned short* __restrict__ vt)
{
    __shared__ __align__(16) unsigned short As[64 * 72];
    __shared__ __align__(16) unsigned short Bs[64 * 72];
    if (blockIdx.z == 0) {
        const int bm = blockIdx.x * 64, bn = blockIdx.y * 64;
        const unsigned short* B = (bm < 512) ? wgt : wctx;
        const float* bias = (bm < 512) ? bgt : bctx;
        gemm_tile_bf16(in_bf + (long long)bm * 1024, 1024,
                       B + (long long)bn * 1024, 1024, 1024,
                       qk + (long long)bm * 1024 + bn, 1024,
                       bias + bn, As, Bs);
    } else {
        const int g = blockIdx.y;
        const int bn = blockIdx.x * 64;
        gemm_tile_bf16(wconv + (long long)g * 65536, 1024,
                       in_bf + (long long)bn * 1024, 1024, 1024,
                       vt + (long long)g * 98304 + bn, 1536,
                       nullptr, As, Bs);
    }
}

// ---------------------------------------------------------------------------
// Position bias via hi/lo-split MFMA (round 7, verified). Block = 64 pairs.
// ---------------------------------------------------------------------------
__global__ __launch_bounds__(256) void pos_bias_kernel(
    const float* __restrict__ box, const float* __restrict__ ctx_box,
    const float* __restrict__ w_gt, const float* __restrict__ b_gt,
    const float* __restrict__ w_ctx, const float* __restrict__ b_ctx,
    _Float16* __restrict__ bias_gt, _Float16* __restrict__ bias_ctx)
{
    const bool first = (blockIdx.z == 0);
    const float* boxA = first ? box : ctx_box;
    const float* boxB = first ? ctx_box : box;
    const float* w_pos = first ? w_gt : w_ctx;
    const float* b_pos = first ? b_gt : b_ctx;
    _Float16* out = first ? bias_gt : bias_ctx;
    const int shift = first ? 10 : 9;

    __shared__ __align__(16) unsigned short AsH[64 * 72];
    __shared__ __align__(16) unsigned short AsL[64 * 72];
    __shared__ __align__(16) unsigned short BsH[16 * 72];
    __shared__ __align__(16) unsigned short BsL[16 * 72];

    const int tid = threadIdx.x;

    // stage B: w_pos (16x64 fp32) -> bf16 hi + lo
    {
        const int g = tid >> 4;
        const int d = (tid & 15) * 4;
        float4 wv = *(const float4*)(w_pos + g * 64 + d);
        ushort4 h, l;
        h.x = f32_bf16_rne(wv.x); l.x = f32_bf16_rne(wv.x - bf16_f32(h.x));
        h.y = f32_bf16_rne(wv.y); l.y = f32_bf16_rne(wv.y - bf16_f32(h.y));
        h.z = f32_bf16_rne(wv.z); l.z = f32_bf16_rne(wv.z - bf16_f32(h.z));
        h.w = f32_bf16_rne(wv.w); l.w = f32_bf16_rne(wv.w - bf16_f32(h.w));
        *(ushort4*)&BsH[g * 72 + d] = h;
        *(ushort4*)&BsL[g * 72 + d] = l;
    }

    // stage A: relu(sin/cos) embeddings, hi + lo
    const long long pbase = (long long)blockIdx.x * 64;
    {
        const int pl = tid & 63;
        const int p = tid >> 6;          // wave-uniform: no divergence
        const long long pair = pbase + pl;
        const int i = (int)(pair >> shift);
        const int j = (int)(pair & ((1 << shift) - 1));
        float4 ba = *(const float4*)(boxA + i * 4);
        float4 bb = *(const float4*)(boxB + j * 4);
        float posv;
        if (p == 0) {
            float bw = ba.z - ba.x + 1.f;
            float cx = 0.5f * (ba.x + ba.z), ccx = 0.5f * (bb.x + bb.z);
            posv = __logf(fmaxf(fabsf((cx - ccx) / bw), 1e-3f));
        } else if (p == 1) {
            float bh = ba.w - ba.y + 1.f;
            float cy = 0.5f * (ba.y + ba.w), ccy = 0.5f * (bb.y + bb.w);
            posv = __logf(fmaxf(fabsf((cy - ccy) / bh), 1e-3f));
        } else if (p == 2) {
            float bw = ba.z - ba.x + 1.f, cbw = bb.z - bb.x + 1.f;
            posv = __logf(cbw / bw);
        } else {
            float bh = ba.w - ba.y + 1.f, cbh = bb.w - bb.y + 1.f;
            posv = __logf(cbh / bh);
        }
        // 100 * 1000^(-f/8)
        const float w100[8] = {100.f, 42.169650342f, 17.782794100f, 7.498942093f,
                               3.162277660f, 1.333521432f, 0.562341325f, 0.237137371f};
        short8 sh, sl, ch, cl;
        #pragma unroll
        for (int f = 0; f < 8; ++f) {
            float s, c;
            __sincosf(posv * w100[f], &s, &c);
            s = fmaxf(s, 0.f);
            c = fmaxf(c, 0.f);
            unsigned short hs = f32_bf16_rne(s);
            unsigned short hc = f32_bf16_rne(c);
            sh[f] = (short)hs; sl[f] = (short)f32_bf16_rne(s - bf16_f32(hs));
            ch[f] = (short)hc; cl[f] = (short)f32_bf16_rne(c - bf16_f32(hc));
        }
        *(short8*)&AsH[pl * 72 + p * 16]     = sh;   // d = p*16 + f      (sin)
        *(short8*)&AsH[pl * 72 + p * 16 + 8] = ch;   // d = p*16 + 8 + f  (cos)
        *(short8*)&AsL[pl * 72 + p * 16]     = sl;
        *(short8*)&AsL[pl * 72 + p * 16 + 8] = cl;
    }
    __syncthreads();

    // MFMA: wave w -> pairs w*16..+15 (rows) x groups (cols), K=64, 3 chains
    const int lane = tid & 63;
    const int w = tid >> 6;
    const int m = lane & 15;
    const int quad = lane >> 4;
    const unsigned short* apH = &AsH[(w * 16 + m) * 72 + quad * 8];
    const unsigned short* apL = &AsL[(w * 16 + m) * 72 + quad * 8];
    const unsigned short* bpH = &BsH[m * 72 + quad * 8];
    const unsigned short* bpL = &BsL[m * 72 + quad * 8];
    floatx4 acc = {0.f, 0.f, 0.f, 0.f};
    acc = mfma16(*(const short8*)apH,        *(const short8*)bpH,        acc);
    acc = mfma16(*(const short8*)(apH + 32), *(const short8*)(bpH + 32), acc);
    acc = mfma16(*(const short8*)apH,        *(const short8*)bpL,        acc);
    acc = mfma16(*(const short8*)(apH + 32), *(const short8*)(bpL + 32), acc);
    acc = mfma16(*(const short8*)apL,        *(const short8*)bpH,        acc);
    acc = mfma16(*(const short8*)(apL + 32), *(const short8*)(bpH + 32), acc);

    // C: row = pair local quad*4+r, col = group m
    const float bpv = b_pos[m];
    half4 o;
    #pragma unroll
    for (int r = 0; r < 4; ++r)
        o[r] = (_Float16)__logf(fmaxf(acc[r] + bpv, 1e-6f));
    *(half4*)(out + (long long)m * 524288 + pbase + w * 16 + quad * 4) = o;
}

// ---------------------------------------------------------------------------
// Fused scores + bias + softmax + output GEMM body. Block = (g, 16 A-rows).
// B-fragments (k rows / vt rows) loaded DIRECT from global (L2-resident):
// the MFMA B-operand layout X[lane&15][quad*8+j] is a plain 16B load.
// No LDS tile, no staging barriers — only wpack handoff + softmax barriers.
// ---------------------------------------------------------------------------
template <int NC>
__device__ __forceinline__ void attn_body(
    int g, int bx,
    const unsigned short* __restrict__ qA, const unsigned short* __restrict__ qB,
    const _Float16* __restrict__ bias, const unsigned short* __restrict__ vt,
    int vt_colbase, const float* __restrict__ b_conv, float* __restrict__ outp,
    unsigned short* wpack, float* redA, float* redB)
{
    constexpr int NCOL = NC * 64;
    constexpr int WS = NCOL + 8;

    const int bm = bx * 16;
    const int tid = threadIdx.x;
    const int lane = tid & 63;
    const int w = tid >> 6;
    const int m = lane & 15;
    const int quad = lane >> 4;

    const _Float16* bias_g = bias + (long long)g * 524288
                           + (long long)(bm + quad * 4) * NCOL + w * 16 + m;

    // A-fragments (q rows), loaded once
    const unsigned short* ap = qA + (long long)(bm + m) * 1024 + g * 64 + quad * 8;
    short8 aq0 = *(const short8*)ap;
    short8 aq1 = *(const short8*)(ap + 32);

    // B-fragment base: score col = c*64 + w*16 + m  ->  qB row (c*64 + w*16 + m)
    const unsigned short* bbase = qB + (long long)(w * 16 + m) * 1024 + g * 64 + quad * 8;

    float v[NC][4];
    short8 b0 = *(const short8*)bbase;
    short8 b1 = *(const short8*)(bbase + 32);

    #pragma unroll
    for (int c = 0; c < NC; ++c) {
        short8 nb0, nb1;
        if (c + 1 < NC) {
            const unsigned short* nb = bbase + (long long)(c + 1) * 65536;
            nb0 = *(const short8*)nb;
            nb1 = *(const short8*)(nb + 32);
        }
        float bv[4];
        #pragma unroll
        for (int r = 0; r < 4; ++r)
            bv[r] = (float)bias_g[(long long)r * NCOL + c * 64];
        floatx4 acc = {0.f, 0.f, 0.f, 0.f};
        acc = mfma16(aq0, b0, acc);
        acc = mfma16(aq1, b1, acc);
        #pragma unroll
        for (int r = 0; r < 4; ++r)
            v[c][r] = fmaf(0.125f, acc[r], bv[r]);
        b0 = nb0; b1 = nb1;
    }

    // ---- softmax over rows (row = quad*4+r), cols split: wave w, m, chunk c
    float rmax[4];
    #pragma unroll
    for (int r = 0; r < 4; ++r) {
        float mx = v[0][r];
        #pragma unroll
        for (int c = 1; c < NC; ++c) mx = fmaxf(mx, v[c][r]);
        #pragma unroll
        for (int off = 1; off < 16; off <<= 1)
            mx = fmaxf(mx, __shfl_xor(mx, off, 64));
        rmax[r] = mx;
    }
    if (m == 0) {
        #pragma unroll
        for (int r = 0; r < 4; ++r) redA[w * 16 + quad * 4 + r] = rmax[r];
    }
    __syncthreads();
    #pragma unroll
    for (int r = 0; r < 4; ++r)
        rmax[r] = fmaxf(fmaxf(redA[quad*4+r], redA[16 + quad*4+r]),
                        fmaxf(redA[32 + quad*4+r], redA[48 + quad*4+r]));

    float rsum[4] = {0.f, 0.f, 0.f, 0.f};
    #pragma unroll
    for (int c = 0; c < NC; ++c)
        #pragma unroll
        for (int r = 0; r < 4; ++r) {
            v[c][r] = __expf(v[c][r] - rmax[r]);
            rsum[r] += v[c][r];
        }
    #pragma unroll
    for (int r = 0; r < 4; ++r)
        #pragma unroll
        for (int off = 1; off < 16; off <<= 1)
            rsum[r] += __shfl_xor(rsum[r], off, 64);
    if (m == 0) {
        #pragma unroll
        for (int r = 0; r < 4; ++r) redB[w * 16 + quad * 4 + r] = rsum[r];
    }
    __syncthreads();
    float rinv[4];
    #pragma unroll
    for (int r = 0; r < 4; ++r)
        rinv[r] = 1.f / (redB[quad*4+r] + redB[16 + quad*4+r] +
                         redB[32 + quad*4+r] + redB[48 + quad*4+r]);

    #pragma unroll
    for (int c = 0; c < NC; ++c)
        #pragma unroll
        for (int r = 0; r < 4; ++r)
            wpack[(quad * 4 + r) * WS + c * 64 + w * 16 + m] =
                f32_bf16_rne(v[c][r] * rinv[r]);

    // prefetch vt chunk 0 while waiting on wpack
    const unsigned short* vbase = vt + (long long)g * 98304
                                + (long long)(w * 16 + m) * 1536 + vt_colbase + quad * 8;
    short8 vb0 = *(const short8*)vbase;
    short8 vb1 = *(const short8*)(vbase + 32);

    __syncthreads();   // wpack writes visible to all waves

    // ---- phase 3: out = W @ vt^T, B-fragments direct from global
    floatx4 oacc = {0.f, 0.f, 0.f, 0.f};
    const unsigned short* awp = wpack + m * WS + quad * 8;
    #pragma unroll
    for (int kc = 0; kc < NC; ++kc) {
        short8 nv0, nv1;
        if (kc + 1 < NC) {
            const unsigned short* nv = vbase + (kc + 1) * 64;
            nv0 = *(const short8*)nv;
            nv1 = *(const short8*)(nv + 32);
        }
        short8 a0 = *(const short8*)(awp + kc * 64);
        short8 a1 = *(const short8*)(awp + kc * 64 + 32);
        oacc = mfma16(a0, vb0, oacc);
        oacc = mfma16(a1, vb1, oacc);
        vb0 = nv0; vb1 = nv1;
    }

    const int o = w * 16 + m;
    const float bc = b_conv[g * 64 + o];
    #pragma unroll
    for (int r = 0; r < 4; ++r)
        outp[(long long)(bm + quad * 4 + r) * 1024 + g * 64 + o] = oacc[r] + bc;
}

// Merged both directions: z<16 -> gt (g=z, 32 row-blocks), z>=16 -> ctx.
__global__ __launch_bounds__(256) void attn_out_kernel(
    const unsigned short* __restrict__ qk,
    const _Float16* __restrict__ bias_gt, const _Float16* __restrict__ bias_ctx,
    const unsigned short* __restrict__ vt, const float* __restrict__ b_conv,
    float* __restrict__ out_gt, float* __restrict__ out_ctx)
{
    __shared__ __align__(16) unsigned short wpack[16 * 1032];
    __shared__ float redA[64], redB[64];

    const int z = blockIdx.z;
    if (z < 16) {
        if (blockIdx.x >= 32) return;      // block-uniform exit
        attn_body<16>(z, blockIdx.x, qk, qk + 524288LL, bias_gt, vt, 512,
                      b_conv, out_gt, wpack, redA, redB);
    } else {
        attn_body<8>(z - 16, blockIdx.x, qk + 524288LL, qk, bias_ctx, vt, 0,
                     b_conv, out_ctx, wpack, redA, redB);
    }
}

// ---------------------------------------------------------------------------
__global__ __launch_bounds__(256) void conv5_f32_bf16(
    const float* s0, unsigned short* d0, int n0,
    const float* s1, unsigned short* d1, int n1,
    const float* s2, unsigned short* d2, int n2,
    const float* s3, unsigned short* d3, int n3,
    const float* s4, unsigned short* d4, int n4)
{
    const float* s; unsigned short* d; int n;
    switch (blockIdx.y) {
        case 0: s = s0; d = d0; n = n0; break;
        case 1: s = s1; d = d1; n = n1; break;
        case 2: s = s2; d = d2; n = n2; break;
        case 3: s = s3; d = d3; n = n3; break;
        default: s = s4; d = d4; n = n4; break;
    }
    int idx = (blockIdx.x * 256 + threadIdx.x) * 4;
    if (idx < n) {
        float4 v = *(const float4*)(s + idx);
        ushort4 o;
        o.x = f32_bf16_rne(v.x); o.y = f32_bf16_rne(v.y);
        o.z = f32_bf16_rne(v.z); o.w = f32_bf16_rne(v.w);
        *(ushort4*)(d + idx) = o;
    }
}

// ---------------------------------------------------------------------------
extern "C" void kernel_launch(void* const* d_in, const int* in_sizes, int n_in,
                              void* d_out, int out_size, void* d_ws, size_t ws_size,
                              hipStream_t stream)
{
    const float* feat     = (const float*)d_in[0];
    const float* ctx_feat = (const float*)d_in[1];
    const float* box      = (const float*)d_in[2];
    const float* ctx_box  = (const float*)d_in[3];
    const float* w_fc_gt  = (const float*)d_in[4];
    const float* b_fc_gt  = (const float*)d_in[5];
    const float* w_fc_ctx = (const float*)d_in[6];
    const float* b_fc_ctx = (const float*)d_in[7];
    const float* w_pos_gt = (const float*)d_in[8];
    const float* b_pos_gt = (const float*)d_in[9];
    const float* w_pos_ctx= (const float*)d_in[10];
    const float* b_pos_ctx= (const float*)d_in[11];
    const float* w_conv   = (const float*)d_in[12];
    const float* b_conv   = (const float*)d_in[13];

    float* ws = (float*)d_ws;
    unsigned short* in_bf   = (unsigned short*)ws;           // 1572864 s
    unsigned short* ctx_bf  = in_bf + 524288LL;
    unsigned short* qk_bf   = in_bf + 1572864LL;             // 1572864 s
    _Float16* bias_gt  = (_Float16*)(ws + 1572864LL);        // 8388608 h
    _Float16* bias_ctx = (_Float16*)(ws + 5767168LL);        // 8388608 h
    unsigned short* wconv_bf = (unsigned short*)(ws + 9961472LL);   // 1048576 s
    unsigned short* vt_bf    = (unsigned short*)(ws + 10485760LL);  // 1572864 s
    unsigned short* wfcgt_bf = (unsigned short*)(ws + 11272192LL);  // 1048576 s
    unsigned short* wfcctx_bf= wfcgt_bf + 1048576LL;                // 1048576 s

    float* out_gt  = (float*)d_out;
    float* out_ctx = (float*)d_out + 524288LL;

    // 1) casts
    hipLaunchKernelGGL(conv5_f32_bf16, dim3(1024, 5), dim3(256), 0, stream,
                       feat, in_bf, 524288,
                       ctx_feat, ctx_bf, 1048576,
                       w_fc_gt, wfcgt_bf, 1048576,
                       w_fc_ctx, wfcctx_bf, 1048576,
                       w_conv, wconv_bf, 1048576);

    // 2) position bias (fp16) via hi/lo-split MFMA
    hipLaunchKernelGGL(pos_bias_kernel, dim3(8192, 1, 2), dim3(256), 0, stream,
                       box, ctx_box, w_pos_gt, b_pos_gt, w_pos_ctx, b_pos_ctx,
                       bias_gt, bias_ctx);

    // 3) merged q/k projection + v-projection
    hipLaunchKernelGGL(projvt_kernel, dim3(24, 16, 2), dim3(256), 0, stream,
                       in_bf, wfcgt_bf, wfcctx_bf, b_fc_gt, b_fc_ctx, qk_bf,
                       wconv_bf, vt_bf);

    // 4) fused scores+softmax+output, both directions
    hipLaunchKernelGGL(attn_out_kernel, dim3(64, 1, 32), dim3(256), 0, stream,
                       qk_bf, bias_gt, bias_ctx, vt_bf, b_conv, out_gt, out_ctx);
}

// Round 9
// 177.846 us; speedup vs baseline: 1.0130x; 1.0130x over previous
//
#include <hip/hip_runtime.h>
#include <math.h>

// M=512, N=1024, G=16, D=64, C=1024. All GEMM-shaped work on bf16 MFMA 16x16x32.
// pos_bias uses a bf16 hi/lo (Dekker) split MFMA (rounds 4/6: plain bf16 dot
// error ~2e-4 sign-flips entries in log-clip floor rows -> absmax 0.205).
//
// Round 9: attn_body stages its fp16 bias slice (16 x NCOL) into LDS with
// coalesced 16B loads (r8 evidence: 64 scalar 2B global loads/thread left the
// kernel latency-bound at 1.1 TB/s, MfmaUtil 3.4%). The bias LDS aliases the
// wpack buffer (2 barriers separate last bias read from first wpack write).
//
// Pipeline (4 launches):
//   conv5    : fp32->bf16 casts
//   pos_bias : trig -> hi/lo LDS -> 6x MFMA -> log -> fp16 bias planes
//   projvt   : z=0: qk = [feat;ctx] @ [w_fc]^T + b ; z=1: vt = w_conv @ [feat;ctx]^T
//   attn_out : bias->LDS; scores (direct-B MFMA) -> softmax (regs) ->
//              bf16 weights in LDS -> out-GEMM vs vt (direct-B) -> d_out
//
// Workspace (float offsets), total 12,320,768 floats = 49.3 MB:
//   [0,1572864)        : shorts: in_bf (feat 524288 + ctx 1048576), qk_bf (1572864)
//   [1572864,5767168)  : bias_gt  fp16 (16,512,1024)
//   [5767168,9961472)  : bias_ctx fp16 (16,1024,512)
//   [9961472,10485760) : wconv_bf (1048576 s)
//   [10485760,11272192): vt_bf (G,64,1536) shorts; cols 0..511 feat, 512..1535 ctx
//   [11272192,12320768): wfcgt_bf + wfcctx_bf

typedef __attribute__((ext_vector_type(8))) short short8;   // 8 bf16 = 4 VGPRs
typedef __attribute__((ext_vector_type(4))) float floatx4;
typedef __attribute__((ext_vector_type(4))) _Float16 half4;

__device__ inline unsigned short f32_bf16_rne(float x) {
    union { float f; unsigned u; } v; v.f = x;
    unsigned u = v.u;
    return (unsigned short)((u + 0x7fffu + ((u >> 16) & 1u)) >> 16);
}

__device__ inline float bf16_f32(unsigned short h) {
    union { unsigned u; float f; } v; v.u = (unsigned)h << 16;
    return v.f;
}

__device__ __forceinline__ floatx4 mfma16(short8 a, short8 b, floatx4 c) {
    return __builtin_amdgcn_mfma_f32_16x16x32_bf16(a, b, c, 0, 0, 0);
}

// ---------------------------------------------------------------------------
// 64x64 tile NT bf16 GEMM core. 4 waves, 32x32 quadrant each, BK=64 with
// distance-2 register prefetch. Writes bf16. K%128==0, lda/ldb%8==0.
// ---------------------------------------------------------------------------
__device__ __forceinline__ void gemm_tile_bf16(
    const unsigned short* __restrict__ Ab, int lda,
    const unsigned short* __restrict__ Bb, int ldb, int K,
    unsigned short* __restrict__ Cb, int ldc,
    const float* __restrict__ biasvec,
    unsigned short* As, unsigned short* Bs)
{
    const int tid = threadIdx.x;
    const int lr = tid >> 2;
    const int lk = (tid & 3) * 8;
    const int lane = tid & 63;
    const int wave = tid >> 6;
    const int qr = (wave >> 1) * 32;
    const int qc = (wave & 1) * 32;
    const int m = lane & 15;
    const int quad = lane >> 4;

    const unsigned short* Ap = Ab + (long long)lr * lda + lk;
    const unsigned short* Bp = Bb + (long long)lr * ldb + lk;
    unsigned short* AsW = As + lr * 72 + lk;
    unsigned short* BsW = Bs + lr * 72 + lk;
    const unsigned short* a0p = As + (qr + m) * 72 + quad * 8;
    const unsigned short* b0p = Bs + (qc + m) * 72 + quad * 8;

    floatx4 acc00 = {0.f,0.f,0.f,0.f}, acc01 = {0.f,0.f,0.f,0.f};
    floatx4 acc10 = {0.f,0.f,0.f,0.f}, acc11 = {0.f,0.f,0.f,0.f};

    // distance-2 pipeline: p* = chunk to store this iter, q* = chunk after
    int4 pa0 = *(const int4*)Ap;
    int4 pa1 = *(const int4*)(Ap + 32);
    int4 pb0 = *(const int4*)Bp;
    int4 pb1 = *(const int4*)(Bp + 32);
    int4 qa0 = *(const int4*)(Ap + 64);
    int4 qa1 = *(const int4*)(Ap + 96);
    int4 qb0 = *(const int4*)(Bp + 64);
    int4 qb1 = *(const int4*)(Bp + 96);

    for (int k0 = 0; ; ) {
        __syncthreads();
        *(int4*)AsW        = pa0;
        *(int4*)(AsW + 32) = pa1;
        *(int4*)BsW        = pb0;
        *(int4*)(BsW + 32) = pb1;
        __syncthreads();
        pa0 = qa0; pa1 = qa1; pb0 = qb0; pb1 = qb1;
        const int kf = k0 + 128;
        if (kf < K) {            // prefetch two chunks ahead
            qa0 = *(const int4*)(Ap + kf);
            qa1 = *(const int4*)(Ap + kf + 32);
            qb0 = *(const int4*)(Bp + kf);
            qb1 = *(const int4*)(Bp + kf + 32);
        }
        #pragma unroll
        for (int kk = 0; kk < 64; kk += 32) {
            short8 a0 = *(const short8*)(a0p + kk);
            short8 a1 = *(const short8*)(a0p + 16 * 72 + kk);
            short8 b0 = *(const short8*)(b0p + kk);
            short8 b1 = *(const short8*)(b0p + 16 * 72 + kk);
            acc00 = mfma16(a0, b0, acc00);
            acc01 = mfma16(a0, b1, acc01);
            acc10 = mfma16(a1, b0, acc10);
            acc11 = mfma16(a1, b1, acc11);
        }
        k0 += 64;
        if (k0 >= K) break;
    }

    float bias0 = 0.f, bias1 = 0.f;
    if (biasvec) { bias0 = biasvec[qc + m]; bias1 = biasvec[qc + 16 + m]; }

    const floatx4 accs[2][2] = { {acc00, acc01}, {acc10, acc11} };
    #pragma unroll
    for (int i = 0; i < 2; ++i)
        #pragma unroll
        for (int r = 0; r < 4; ++r) {
            const int lrow = qr + i * 16 + quad * 4 + r;
            #pragma unroll
            for (int j = 0; j < 2; ++j) {
                const int lcol = qc + j * 16 + m;
                float val = accs[i][j][r] + (j ? bias1 : bias0);
                Cb[(long long)lrow * ldc + lcol] = f32_bf16_rne(val);
            }
        }
}

// ---------------------------------------------------------------------------
// Merged proj + vt. z=0: qk rows 0..1535 = [feat;ctx] @ w_fc^T + b (w per half).
// z=1: vt[g][o][c] = w_conv[g][o] . in[c], c over 1536 concat rows.
// ---------------------------------------------------------------------------
__global__ __launch_bounds__(256) void projvt_kernel(
    const unsigned short* __restrict__ in_bf, const unsigned short* __restrict__ wgt,
    const unsigned short* __restrict__ wctx,
    const float* __restrict__ bgt, const float* __restrict__ bctx,
    unsigned short* __restrict__ qk,
    const unsigned short* __restrict__ wconv, unsigned short* __restrict__ vt)
{
    __shared__ __align__(16) unsigned short As[64 * 72];
    __shared__ __align__(16) unsigned short Bs[64 * 72];
    if (blockIdx.z == 0) {
        const int bm = blockIdx.x * 64, bn = blockIdx.y * 64;
        const unsigned short* B = (bm < 512) ? wgt : wctx;
        const float* bias = (bm < 512) ? bgt : bctx;
        gemm_tile_bf16(in_bf + (long long)bm * 1024, 1024,
                       B + (long long)bn * 1024, 1024, 1024,
                       qk + (long long)bm * 1024 + bn, 1024,
                       bias + bn, As, Bs);
    } else {
        const int g = blockIdx.y;
        const int bn = blockIdx.x * 64;
        gemm_tile_bf16(wconv + (long long)g * 65536, 1024,
                       in_bf + (long long)bn * 1024, 1024, 1024,
                       vt + (long long)g * 98304 + bn, 1536,
                       nullptr, As, Bs);
    }
}

// ---------------------------------------------------------------------------
// Position bias via hi/lo-split MFMA (round 7, verified). Block = 64 pairs.
// ---------------------------------------------------------------------------
__global__ __launch_bounds__(256) void pos_bias_kernel(
    const float* __restrict__ box, const float* __restrict__ ctx_box,
    const float* __restrict__ w_gt, const float* __restrict__ b_gt,
    const float* __restrict__ w_ctx, const float* __restrict__ b_ctx,
    _Float16* __restrict__ bias_gt, _Float16* __restrict__ bias_ctx)
{
    const bool first = (blockIdx.z == 0);
    const float* boxA = first ? box : ctx_box;
    const float* boxB = first ? ctx_box : box;
    const float* w_pos = first ? w_gt : w_ctx;
    const float* b_pos = first ? b_gt : b_ctx;
    _Float16* out = first ? bias_gt : bias_ctx;
    const int shift = first ? 10 : 9;

    __shared__ __align__(16) unsigned short AsH[64 * 72];
    __shared__ __align__(16) unsigned short AsL[64 * 72];
    __shared__ __align__(16) unsigned short BsH[16 * 72];
    __shared__ __align__(16) unsigned short BsL[16 * 72];

    const int tid = threadIdx.x;

    // stage B: w_pos (16x64 fp32) -> bf16 hi + lo
    {
        const int g = tid >> 4;
        const int d = (tid & 15) * 4;
        float4 wv = *(const float4*)(w_pos + g * 64 + d);
        ushort4 h, l;
        h.x = f32_bf16_rne(wv.x); l.x = f32_bf16_rne(wv.x - bf16_f32(h.x));
        h.y = f32_bf16_rne(wv.y); l.y = f32_bf16_rne(wv.y - bf16_f32(h.y));
        h.z = f32_bf16_rne(wv.z); l.z = f32_bf16_rne(wv.z - bf16_f32(h.z));
        h.w = f32_bf16_rne(wv.w); l.w = f32_bf16_rne(wv.w - bf16_f32(h.w));
        *(ushort4*)&BsH[g * 72 + d] = h;
        *(ushort4*)&BsL[g * 72 + d] = l;
    }

    // stage A: relu(sin/cos) embeddings, hi + lo
    const long long pbase = (long long)blockIdx.x * 64;
    {
        const int pl = tid & 63;
        const int p = tid >> 6;          // wave-uniform: no divergence
        const long long pair = pbase + pl;
        const int i = (int)(pair >> shift);
        const int j = (int)(pair & ((1 << shift) - 1));
        float4 ba = *(const float4*)(boxA + i * 4);
        float4 bb = *(const float4*)(boxB + j * 4);
        float posv;
        if (p == 0) {
            float bw = ba.z - ba.x + 1.f;
            float cx = 0.5f * (ba.x + ba.z), ccx = 0.5f * (bb.x + bb.z);
            posv = __logf(fmaxf(fabsf((cx - ccx) / bw), 1e-3f));
        } else if (p == 1) {
            float bh = ba.w - ba.y + 1.f;
            float cy = 0.5f * (ba.y + ba.w), ccy = 0.5f * (bb.y + bb.w);
            posv = __logf(fmaxf(fabsf((cy - ccy) / bh), 1e-3f));
        } else if (p == 2) {
            float bw = ba.z - ba.x + 1.f, cbw = bb.z - bb.x + 1.f;
            posv = __logf(cbw / bw);
        } else {
            float bh = ba.w - ba.y + 1.f, cbh = bb.w - bb.y + 1.f;
            posv = __logf(cbh / bh);
        }
        // 100 * 1000^(-f/8)
        const float w100[8] = {100.f, 42.169650342f, 17.782794100f, 7.498942093f,
                               3.162277660f, 1.333521432f, 0.562341325f, 0.237137371f};
        short8 sh, sl, ch, cl;
        #pragma unroll
        for (int f = 0; f < 8; ++f) {
            float s, c;
            __sincosf(posv * w100[f], &s, &c);
            s = fmaxf(s, 0.f);
            c = fmaxf(c, 0.f);
            unsigned short hs = f32_bf16_rne(s);
            unsigned short hc = f32_bf16_rne(c);
            sh[f] = (short)hs; sl[f] = (short)f32_bf16_rne(s - bf16_f32(hs));
            ch[f] = (short)hc; cl[f] = (short)f32_bf16_rne(c - bf16_f32(hc));
        }
        *(short8*)&AsH[pl * 72 + p * 16]     = sh;   // d = p*16 + f      (sin)
        *(short8*)&AsH[pl * 72 + p * 16 + 8] = ch;   // d = p*16 + 8 + f  (cos)
        *(short8*)&AsL[pl * 72 + p * 16]     = sl;
        *(short8*)&AsL[pl * 72 + p * 16 + 8] = cl;
    }
    __syncthreads();

    // MFMA: wave w -> pairs w*16..+15 (rows) x groups (cols), K=64, 3 chains
    const int lane = tid & 63;
    const int w = tid >> 6;
    const int m = lane & 15;
    const int quad = lane >> 4;
    const unsigned short* apH = &AsH[(w * 16 + m) * 72 + quad * 8];
    const unsigned short* apL = &AsL[(w * 16 + m) * 72 + quad * 8];
    const unsigned short* bpH = &BsH[m * 72 + quad * 8];
    const unsigned short* bpL = &BsL[m * 72 + quad * 8];
    floatx4 acc = {0.f, 0.f, 0.f, 0.f};
    acc = mfma16(*(const short8*)apH,        *(const short8*)bpH,        acc);
    acc = mfma16(*(const short8*)(apH + 32), *(const short8*)(bpH + 32), acc);
    acc = mfma16(*(const short8*)apH,        *(const short8*)bpL,        acc);
    acc = mfma16(*(const short8*)(apH + 32), *(const short8*)(bpL + 32), acc);
    acc = mfma16(*(const short8*)apL,        *(const short8*)bpH,        acc);
    acc = mfma16(*(const short8*)(apL + 32), *(const short8*)(bpH + 32), acc);

    // C: row = pair local quad*4+r, col = group m
    const float bpv = b_pos[m];
    half4 o;
    #pragma unroll
    for (int r = 0; r < 4; ++r)
        o[r] = (_Float16)__logf(fmaxf(acc[r] + bpv, 1e-6f));
    *(half4*)(out + (long long)m * 524288 + pbase + w * 16 + quad * 4) = o;
}

// ---------------------------------------------------------------------------
// Fused scores + bias + softmax + output GEMM body. Block = (g, 16 A-rows).
// Bias slice staged into LDS (aliases wpack; 2 barriers separate last bias
// read from first wpack write). B-fragments (k/vt rows) direct from global.
// ---------------------------------------------------------------------------
template <int NC>
__device__ __forceinline__ void attn_body(
    int g, int bx,
    const unsigned short* __restrict__ qA, const unsigned short* __restrict__ qB,
    const _Float16* __restrict__ bias, const unsigned short* __restrict__ vt,
    int vt_colbase, const float* __restrict__ b_conv, float* __restrict__ outp,
    unsigned short* wpack, float* redA, float* redB)
{
    constexpr int NCOL = NC * 64;
    constexpr int WS = NCOL + 8;
    constexpr int SHIFT = (NC == 16) ? 10 : 9;

    const int bm = bx * 16;
    const int tid = threadIdx.x;
    const int lane = tid & 63;
    const int w = tid >> 6;
    const int m = lane & 15;
    const int quad = lane >> 4;

    // ---- stage bias slice (16 x NCOL fp16) into LDS, coalesced 16B loads
    _Float16* bb = (_Float16*)wpack;
    {
        const _Float16* bsrc = bias + (long long)g * 524288 + (long long)bm * NCOL;
        #pragma unroll
        for (int i = 0; i < (16 * NCOL) / (256 * 8); ++i) {
            const int idx = (i * 256 + tid) * 8;
            const int row = idx >> SHIFT;
            const int col = idx & (NCOL - 1);
            *(int4*)(bb + row * WS + col) = *(const int4*)(bsrc + idx);
        }
    }

    // A-fragments (q rows), loaded once (global, overlaps staging)
    const unsigned short* ap = qA + (long long)(bm + m) * 1024 + g * 64 + quad * 8;
    short8 aq0 = *(const short8*)ap;
    short8 aq1 = *(const short8*)(ap + 32);

    // B-fragment base: score col = c*64 + w*16 + m  ->  qB row (c*64 + w*16 + m)
    const unsigned short* bbase = qB + (long long)(w * 16 + m) * 1024 + g * 64 + quad * 8;
    short8 b0 = *(const short8*)bbase;
    short8 b1 = *(const short8*)(bbase + 32);

    __syncthreads();   // bias staged

    const _Float16* brow = bb + (quad * 4) * WS + w * 16 + m;

    float v[NC][4];
    #pragma unroll
    for (int c = 0; c < NC; ++c) {
        short8 nb0, nb1;
        if (c + 1 < NC) {
            const unsigned short* nb = bbase + (long long)(c + 1) * 65536;
            nb0 = *(const short8*)nb;
            nb1 = *(const short8*)(nb + 32);
        }
        float bv[4];
        #pragma unroll
        for (int r = 0; r < 4; ++r)
            bv[r] = (float)brow[r * WS + c * 64];
        floatx4 acc = {0.f, 0.f, 0.f, 0.f};
        acc = mfma16(aq0, b0, acc);
        acc = mfma16(aq1, b1, acc);
        #pragma unroll
        for (int r = 0; r < 4; ++r)
            v[c][r] = fmaf(0.125f, acc[r], bv[r]);
        b0 = nb0; b1 = nb1;
    }

    // ---- softmax over rows (row = quad*4+r), cols split: wave w, m, chunk c
    float rmax[4];
    #pragma unroll
    for (int r = 0; r < 4; ++r) {
        float mx = v[0][r];
        #pragma unroll
        for (int c = 1; c < NC; ++c) mx = fmaxf(mx, v[c][r]);
        #pragma unroll
        for (int off = 1; off < 16; off <<= 1)
            mx = fmaxf(mx, __shfl_xor(mx, off, 64));
        rmax[r] = mx;
    }
    if (m == 0) {
        #pragma unroll
        for (int r = 0; r < 4; ++r) redA[w * 16 + quad * 4 + r] = rmax[r];
    }
    __syncthreads();
    #pragma unroll
    for (int r = 0; r < 4; ++r)
        rmax[r] = fmaxf(fmaxf(redA[quad*4+r], redA[16 + quad*4+r]),
                        fmaxf(redA[32 + quad*4+r], redA[48 + quad*4+r]));

    float rsum[4] = {0.f, 0.f, 0.f, 0.f};
    #pragma unroll
    for (int c = 0; c < NC; ++c)
        #pragma unroll
        for (int r = 0; r < 4; ++r) {
            v[c][r] = __expf(v[c][r] - rmax[r]);
            rsum[r] += v[c][r];
        }
    #pragma unroll
    for (int r = 0; r < 4; ++r)
        #pragma unroll
        for (int off = 1; off < 16; off <<= 1)
            rsum[r] += __shfl_xor(rsum[r], off, 64);
    if (m == 0) {
        #pragma unroll
        for (int r = 0; r < 4; ++r) redB[w * 16 + quad * 4 + r] = rsum[r];
    }
    __syncthreads();   // also: all bias reads complete before wpack overwrite
    float rinv[4];
    #pragma unroll
    for (int r = 0; r < 4; ++r)
        rinv[r] = 1.f / (redB[quad*4+r] + redB[16 + quad*4+r] +
                         redB[32 + quad*4+r] + redB[48 + quad*4+r]);

    #pragma unroll
    for (int c = 0; c < NC; ++c)
        #pragma unroll
        for (int r = 0; r < 4; ++r)
            wpack[(quad * 4 + r) * WS + c * 64 + w * 16 + m] =
                f32_bf16_rne(v[c][r] * rinv[r]);

    // prefetch vt chunk 0 while waiting on wpack
    const unsigned short* vbase = vt + (long long)g * 98304
                                + (long long)(w * 16 + m) * 1536 + vt_colbase + quad * 8;
    short8 vb0 = *(const short8*)vbase;
    short8 vb1 = *(const short8*)(vbase + 32);

    __syncthreads();   // wpack writes visible to all waves

    // ---- phase 3: out = W @ vt^T, B-fragments direct from global
    floatx4 oacc = {0.f, 0.f, 0.f, 0.f};
    const unsigned short* awp = wpack + m * WS + quad * 8;
    #pragma unroll
    for (int kc = 0; kc < NC; ++kc) {
        short8 nv0, nv1;
        if (kc + 1 < NC) {
            const unsigned short* nv = vbase + (kc + 1) * 64;
            nv0 = *(const short8*)nv;
            nv1 = *(const short8*)(nv + 32);
        }
        short8 a0 = *(const short8*)(awp + kc * 64);
        short8 a1 = *(const short8*)(awp + kc * 64 + 32);
        oacc = mfma16(a0, vb0, oacc);
        oacc = mfma16(a1, vb1, oacc);
        vb0 = nv0; vb1 = nv1;
    }

    const int o = w * 16 + m;
    const float bc = b_conv[g * 64 + o];
    #pragma unroll
    for (int r = 0; r < 4; ++r)
        outp[(long long)(bm + quad * 4 + r) * 1024 + g * 64 + o] = oacc[r] + bc;
}

// Flat grid, 1536 blocks: [0,512) gt (g = bx>>5, row-block = bx&31),
// [512,1536) ctx (g = (bx-512)>>6, row-block = (bx-512)&63).
__global__ __launch_bounds__(256) void attn_out_kernel(
    const unsigned short* __restrict__ qk,
    const _Float16* __restrict__ bias_gt, const _Float16* __restrict__ bias_ctx,
    const unsigned short* __restrict__ vt, const float* __restrict__ b_conv,
    float* __restrict__ out_gt, float* __restrict__ out_ctx)
{
    __shared__ __align__(16) unsigned short wpack[16 * 1032];
    __shared__ float redA[64], redB[64];

    const int bx = blockIdx.x;
    if (bx < 512) {
        attn_body<16>(bx >> 5, bx & 31, qk, qk + 524288LL, bias_gt, vt, 512,
                      b_conv, out_gt, wpack, redA, redB);
    } else {
        const int b2 = bx - 512;
        attn_body<8>(b2 >> 6, b2 & 63, qk + 524288LL, qk, bias_ctx, vt, 0,
                     b_conv, out_ctx, wpack, redA, redB);
    }
}

// ---------------------------------------------------------------------------
__global__ __launch_bounds__(256) void conv5_f32_bf16(
    const float* s0, unsigned short* d0, int n0,
    const float* s1, unsigned short* d1, int n1,
    const float* s2, unsigned short* d2, int n2,
    const float* s3, unsigned short* d3, int n3,
    const float* s4, unsigned short* d4, int n4)
{
    const float* s; unsigned short* d; int n;
    switch (blockIdx.y) {
        case 0: s = s0; d = d0; n = n0; break;
        case 1: s = s1; d = d1; n = n1; break;
        case 2: s = s2; d = d2; n = n2; break;
        case 3: s = s3; d = d3; n = n3; break;
        default: s = s4; d = d4; n = n4; break;
    }
    int idx = (blockIdx.x * 256 + threadIdx.x) * 4;
    if (idx < n) {
        float4 v = *(const float4*)(s + idx);
        ushort4 o;
        o.x = f32_bf16_rne(v.x); o.y = f32_bf16_rne(v.y);
        o.z = f32_bf16_rne(v.z); o.w = f32_bf16_rne(v.w);
        *(ushort4*)(d + idx) = o;
    }
}

// ---------------------------------------------------------------------------
extern "C" void kernel_launch(void* const* d_in, const int* in_sizes, int n_in,
                              void* d_out, int out_size, void* d_ws, size_t ws_size,
                              hipStream_t stream)
{
    const float* feat     = (const float*)d_in[0];
    const float* ctx_feat = (const float*)d_in[1];
    const float* box      = (const float*)d_in[2];
    const float* ctx_box  = (const float*)d_in[3];
    const float* w_fc_gt  = (const float*)d_in[4];
    const float* b_fc_gt  = (const float*)d_in[5];
    const float* w_fc_ctx = (const float*)d_in[6];
    const float* b_fc_ctx = (const float*)d_in[7];
    const float* w_pos_gt = (const float*)d_in[8];
    const float* b_pos_gt = (const float*)d_in[9];
    const float* w_pos_ctx= (const float*)d_in[10];
    const float* b_pos_ctx= (const float*)d_in[11];
    const float* w_conv   = (const float*)d_in[12];
    const float* b_conv   = (const float*)d_in[13];

    float* ws = (float*)d_ws;
    unsigned short* in_bf   = (unsigned short*)ws;           // 1572864 s
    unsigned short* ctx_bf  = in_bf + 524288LL;
    unsigned short* qk_bf   = in_bf + 1572864LL;             // 1572864 s
    _Float16* bias_gt  = (_Float16*)(ws + 1572864LL);        // 8388608 h
    _Float16* bias_ctx = (_Float16*)(ws + 5767168LL);        // 8388608 h
    unsigned short* wconv_bf = (unsigned short*)(ws + 9961472LL);   // 1048576 s
    unsigned short* vt_bf    = (unsigned short*)(ws + 10485760LL);  // 1572864 s
    unsigned short* wfcgt_bf = (unsigned short*)(ws + 11272192LL);  // 1048576 s
    unsigned short* wfcctx_bf= wfcgt_bf + 1048576LL;                // 1048576 s

    float* out_gt  = (float*)d_out;
    float* out_ctx = (float*)d_out + 524288LL;

    // 1) casts
    hipLaunchKernelGGL(conv5_f32_bf16, dim3(1024, 5), dim3(256), 0, stream,
                       feat, in_bf, 524288,
                       ctx_feat, ctx_bf, 1048576,
                       w_fc_gt, wfcgt_bf, 1048576,
                       w_fc_ctx, wfcctx_bf, 1048576,
                       w_conv, wconv_bf, 1048576);

    // 2) position bias (fp16) via hi/lo-split MFMA
    hipLaunchKernelGGL(pos_bias_kernel, dim3(8192, 1, 2), dim3(256), 0, stream,
                       box, ctx_box, w_pos_gt, b_pos_gt, w_pos_ctx, b_pos_ctx,
                       bias_gt, bias_ctx);

    // 3) merged q/k projection + v-projection
    hipLaunchKernelGGL(projvt_kernel, dim3(24, 16, 2), dim3(256), 0, stream,
                       in_bf, wfcgt_bf, wfcctx_bf, b_fc_gt, b_fc_ctx, qk_bf,
                       wconv_bf, vt_bf);

    // 4) fused scores+softmax+output, both directions, flat 1536-block grid
    hipLaunchKernelGGL(attn_out_kernel, dim3(1536), dim3(256), 0, stream,
                       qk_bf, bias_gt, bias_ctx, vt_bf, b_conv, out_gt, out_ctx);
}

// Round 10
// 158.234 us; speedup vs baseline: 1.1385x; 1.1239x over previous
//
#include <hip/hip_runtime.h>
#include <math.h>

// M=512, N=1024, G=16, D=64, C=1024. All GEMM-shaped work on bf16 MFMA 16x16x32.
// pos_bias uses a bf16 hi/lo (Dekker) split MFMA (rounds 4/6: plain bf16 dot
// error ~2e-4 sign-flips entries in log-clip floor rows -> absmax 0.205).
//
// Round 10: kill address divergence. r5..r9 attn was stuck at ~40-44 us with
// all pipes idle: every g-slice access = 16 distinct 64B lines per wave-load
// (~16 TA transactions vs 1 coalesced). Fix: qk/vt are stored in MFMA
// FRAGMENT-PACKED layout (written by projvt epilogue via LDS transpose):
//   qk_pack[g][p][part][lane][8shorts]: value X[row][col] with row=p*16+(lane&15),
//   col=part*32+(lane>>4)*8+j, g-slice col base g*64.  p: q rows p=row>>4 (0..31),
//   k rows p=32+(row-512)>>4 (32..95).  vt_pack[g][cc][p][part][lane][8]:
//   p=o>>4, cc=col>>6.  attn loads become base+lane*16B (fully coalesced).
// Also: projvt staging 8 lanes/row; attn out + pos_bias out via LDS->coalesced;
// conv5+pos merged into one launch (3 launches total).
//
// Workspace (float offsets), total 12,320,768 floats = 49.3 MB:
//   [0,1572864)        : shorts: in_bf (feat 524288 + ctx 1048576), qk_pack (1572864)
//   [1572864,5767168)  : bias_gt  fp16 (16,512,1024)
//   [5767168,9961472)  : bias_ctx fp16 (16,1024,512)
//   [9961472,10485760) : wconv_bf (1048576 s)
//   [10485760,11272192): vt_pack (1572864 s)
//   [11272192,12320768): wfcgt_bf + wfcctx_bf

typedef __attribute__((ext_vector_type(8))) short short8;   // 8 bf16 = 4 VGPRs
typedef __attribute__((ext_vector_type(4))) float floatx4;
typedef __attribute__((ext_vector_type(4))) _Float16 half4;

__device__ inline unsigned short f32_bf16_rne(float x) {
    union { float f; unsigned u; } v; v.f = x;
    unsigned u = v.u;
    return (unsigned short)((u + 0x7fffu + ((u >> 16) & 1u)) >> 16);
}

__device__ inline float bf16_f32(unsigned short h) {
    union { unsigned u; float f; } v; v.u = (unsigned)h << 16;
    return v.f;
}

__device__ __forceinline__ floatx4 mfma16(short8 a, short8 b, floatx4 c) {
    return __builtin_amdgcn_mfma_f32_16x16x32_bf16(a, b, c, 0, 0, 0);
}

// ---------------------------------------------------------------------------
// 64x64 tile NT bf16 GEMM core with FRAGMENT-PACKED output. 4 waves, 32x32
// quadrant each, BK=64, distance-2 register prefetch, staging 8 lanes/row.
// Output: out_base[f], f = p_local*1024 + part*512 + lane'*8 + j  (4096 shorts)
// where value C[row][col]: row=p_local*16+(lane'&15), col=part*32+(lane'>>4)*8+j.
// K%128==0, lda/ldb%8==0.
// ---------------------------------------------------------------------------
__device__ __forceinline__ void gemm_tile_pack(
    const unsigned short* __restrict__ Ab, int lda,
    const unsigned short* __restrict__ Bb, int ldb, int K,
    unsigned short* __restrict__ out_base,
    const float* __restrict__ biasvec,
    unsigned short* As, unsigned short* Bs)
{
    const int tid = threadIdx.x;
    const int lr = tid >> 3;          // 0..31 (8 lanes/row -> 8-segment loads)
    const int lk = (tid & 7) * 8;     // 0..56
    const int lane = tid & 63;
    const int wave = tid >> 6;
    const int qr = (wave >> 1) * 32;
    const int qc = (wave & 1) * 32;
    const int m = lane & 15;
    const int quad = lane >> 4;

    const unsigned short* Ap  = Ab + (long long)lr * lda + lk;
    const unsigned short* Ap2 = Ap + 32LL * lda;
    const unsigned short* Bp  = Bb + (long long)lr * ldb + lk;
    const unsigned short* Bp2 = Bp + 32LL * ldb;
    unsigned short* AsW  = As + lr * 72 + lk;
    unsigned short* AsW2 = As + (lr + 32) * 72 + lk;
    unsigned short* BsW  = Bs + lr * 72 + lk;
    unsigned short* BsW2 = Bs + (lr + 32) * 72 + lk;
    const unsigned short* a0p = As + (qr + m) * 72 + quad * 8;
    const unsigned short* b0p = Bs + (qc + m) * 72 + quad * 8;

    floatx4 acc00 = {0.f,0.f,0.f,0.f}, acc01 = {0.f,0.f,0.f,0.f};
    floatx4 acc10 = {0.f,0.f,0.f,0.f}, acc11 = {0.f,0.f,0.f,0.f};

    int4 pa0 = *(const int4*)Ap;
    int4 pa1 = *(const int4*)Ap2;
    int4 pb0 = *(const int4*)Bp;
    int4 pb1 = *(const int4*)Bp2;
    int4 qa0 = *(const int4*)(Ap + 64);
    int4 qa1 = *(const int4*)(Ap2 + 64);
    int4 qb0 = *(const int4*)(Bp + 64);
    int4 qb1 = *(const int4*)(Bp2 + 64);

    for (int k0 = 0; ; ) {
        __syncthreads();
        *(int4*)AsW  = pa0;
        *(int4*)AsW2 = pa1;
        *(int4*)BsW  = pb0;
        *(int4*)BsW2 = pb1;
        __syncthreads();
        pa0 = qa0; pa1 = qa1; pb0 = qb0; pb1 = qb1;
        const int kf = k0 + 128;
        if (kf < K) {
            qa0 = *(const int4*)(Ap + kf);
            qa1 = *(const int4*)(Ap2 + kf);
            qb0 = *(const int4*)(Bp + kf);
            qb1 = *(const int4*)(Bp2 + kf);
        }
        #pragma unroll
        for (int kk = 0; kk < 64; kk += 32) {
            short8 a0 = *(const short8*)(a0p + kk);
            short8 a1 = *(const short8*)(a0p + 16 * 72 + kk);
            short8 b0 = *(const short8*)(b0p + kk);
            short8 b1 = *(const short8*)(b0p + 16 * 72 + kk);
            acc00 = mfma16(a0, b0, acc00);
            acc01 = mfma16(a0, b1, acc01);
            acc10 = mfma16(a1, b0, acc10);
            acc11 = mfma16(a1, b1, acc11);
        }
        k0 += 64;
        if (k0 >= K) break;
    }

    float bias0 = 0.f, bias1 = 0.f;
    if (biasvec) { bias0 = biasvec[qc + m]; bias1 = biasvec[qc + 16 + m]; }

    // transpose to packed layout through As
    __syncthreads();   // all fragment reads done before overwrite
    const floatx4 accs[2][2] = { {acc00, acc01}, {acc10, acc11} };
    #pragma unroll
    for (int i = 0; i < 2; ++i)
        #pragma unroll
        for (int r = 0; r < 4; ++r) {
            const int lrow = qr + i * 16 + quad * 4 + r;
            #pragma unroll
            for (int j = 0; j < 2; ++j) {
                const int lcol = qc + j * 16 + m;
                float val = accs[i][j][r] + (j ? bias1 : bias0);
                As[lrow * 72 + lcol] = f32_bf16_rne(val);
            }
        }
    __syncthreads();
    #pragma unroll
    for (int h = 0; h < 2; ++h) {
        const int f = h * 2048 + tid * 8;
        const int lanep = (f >> 3) & 63;
        const int part = (f >> 9) & 1;
        const int ploc = f >> 10;
        const int row = ploc * 16 + (lanep & 15);
        const int col = part * 32 + ((lanep >> 4) << 3);
        short8 v8 = *(const short8*)&As[row * 72 + col];
        *(short8*)(out_base + f) = v8;      // coalesced 16B/lane
    }
}

// ---------------------------------------------------------------------------
// Merged proj + vt, packed output.
// z=0: qk rows [feat;ctx] @ w_fc^T + b; tile (bx*64 rows, by=g) -> qk_pack.
// z=1: vt[g][o][c]; tile (g=by, cc=bx) -> vt_pack.
// ---------------------------------------------------------------------------
__global__ __launch_bounds__(256) void projvt_kernel(
    const unsigned short* __restrict__ in_bf, const unsigned short* __restrict__ wgt,
    const unsigned short* __restrict__ wctx,
    const float* __restrict__ bgt, const float* __restrict__ bctx,
    unsigned short* __restrict__ qk_pack,
    const unsigned short* __restrict__ wconv, unsigned short* __restrict__ vt_pack)
{
    __shared__ __align__(16) unsigned short As[64 * 72];
    __shared__ __align__(16) unsigned short Bs[64 * 72];
    if (blockIdx.z == 0) {
        const int bm = blockIdx.x * 64;
        const int g = blockIdx.y;
        const unsigned short* B = (bm < 512) ? wgt : wctx;
        const float* bias = (bm < 512) ? bgt : bctx;
        gemm_tile_pack(in_bf + (long long)bm * 1024, 1024,
                       B + (long long)g * 65536, 1024, 1024,
                       qk_pack + ((long long)g * 96 + blockIdx.x * 4) * 1024,
                       bias + g * 64, As, Bs);
    } else {
        const int cc = blockIdx.x;       // 0..23
        const int g = blockIdx.y;
        gemm_tile_pack(wconv + (long long)g * 65536, 1024,
                       in_bf + (long long)cc * 65536, 1024, 1024,
                       vt_pack + ((long long)g * 24 + cc) * 4096,
                       nullptr, As, Bs);
    }
}

// ---------------------------------------------------------------------------
// Merged prep: blocks [0,16384) = pos_bias (hi/lo MFMA, r7-verified math),
// blocks [16384,21504) = fp32->bf16 casts.
// ---------------------------------------------------------------------------
__global__ __launch_bounds__(256) void prep_kernel(
    const float* __restrict__ box, const float* __restrict__ ctx_box,
    const float* __restrict__ w_gt, const float* __restrict__ b_gt,
    const float* __restrict__ w_ctx, const float* __restrict__ b_ctx,
    _Float16* __restrict__ bias_gt, _Float16* __restrict__ bias_ctx,
    const float* s0, unsigned short* d0, int n0,
    const float* s1, unsigned short* d1, int n1,
    const float* s2, unsigned short* d2, int n2,
    const float* s3, unsigned short* d3, int n3,
    const float* s4, unsigned short* d4, int n4)
{
    const int bx = blockIdx.x;
    if (bx >= 16384) {                   // -------- cast branch
        const int bc = bx - 16384;
        const int which = bc >> 10;
        const int xb = bc & 1023;
        const float* s; unsigned short* d; int n;
        switch (which) {
            case 0: s = s0; d = d0; n = n0; break;
            case 1: s = s1; d = d1; n = n1; break;
            case 2: s = s2; d = d2; n = n2; break;
            case 3: s = s3; d = d3; n = n3; break;
            default: s = s4; d = d4; n = n4; break;
        }
        int idx = (xb * 256 + threadIdx.x) * 4;
        if (idx < n) {
            float4 v = *(const float4*)(s + idx);
            ushort4 o;
            o.x = f32_bf16_rne(v.x); o.y = f32_bf16_rne(v.y);
            o.z = f32_bf16_rne(v.z); o.w = f32_bf16_rne(v.w);
            *(ushort4*)(d + idx) = o;
        }
        return;
    }

    // -------- pos_bias branch
    const bool first = (bx < 8192);
    const long long blk = first ? bx : (bx - 8192);
    const float* boxA = first ? box : ctx_box;
    const float* boxB = first ? ctx_box : box;
    const float* w_pos = first ? w_gt : w_ctx;
    const float* b_pos = first ? b_gt : b_ctx;
    _Float16* out = first ? bias_gt : bias_ctx;
    const int shift = first ? 10 : 9;

    __shared__ __align__(16) unsigned short AsH[64 * 72];
    __shared__ __align__(16) unsigned short AsL[64 * 72];
    __shared__ __align__(16) unsigned short BsH[16 * 72];
    __shared__ __align__(16) unsigned short BsL[16 * 72];
    __shared__ _Float16 stg[16 * 68];

    const int tid = threadIdx.x;

    {   // stage B: w_pos hi+lo
        const int g = tid >> 4;
        const int d = (tid & 15) * 4;
        float4 wv = *(const float4*)(w_pos + g * 64 + d);
        ushort4 h, l;
        h.x = f32_bf16_rne(wv.x); l.x = f32_bf16_rne(wv.x - bf16_f32(h.x));
        h.y = f32_bf16_rne(wv.y); l.y = f32_bf16_rne(wv.y - bf16_f32(h.y));
        h.z = f32_bf16_rne(wv.z); l.z = f32_bf16_rne(wv.z - bf16_f32(h.z));
        h.w = f32_bf16_rne(wv.w); l.w = f32_bf16_rne(wv.w - bf16_f32(h.w));
        *(ushort4*)&BsH[g * 72 + d] = h;
        *(ushort4*)&BsL[g * 72 + d] = l;
    }

    const long long pbase = blk * 64;
    {   // stage A: relu(sin/cos) hi+lo
        const int pl = tid & 63;
        const int p = tid >> 6;
        const long long pair = pbase + pl;
        const int i = (int)(pair >> shift);
        const int j = (int)(pair & ((1 << shift) - 1));
        float4 ba = *(const float4*)(boxA + i * 4);
        float4 bb = *(const float4*)(boxB + j * 4);
        float posv;
        if (p == 0) {
            float bw = ba.z - ba.x + 1.f;
            float cx = 0.5f * (ba.x + ba.z), ccx = 0.5f * (bb.x + bb.z);
            posv = __logf(fmaxf(fabsf((cx - ccx) / bw), 1e-3f));
        } else if (p == 1) {
            float bh = ba.w - ba.y + 1.f;
            float cy = 0.5f * (ba.y + ba.w), ccy = 0.5f * (bb.y + bb.w);
            posv = __logf(fmaxf(fabsf((cy - ccy) / bh), 1e-3f));
        } else if (p == 2) {
            float bw = ba.z - ba.x + 1.f, cbw = bb.z - bb.x + 1.f;
            posv = __logf(cbw / bw);
        } else {
            float bh = ba.w - ba.y + 1.f, cbh = bb.w - bb.y + 1.f;
            posv = __logf(cbh / bh);
        }
        const float w100[8] = {100.f, 42.169650342f, 17.782794100f, 7.498942093f,
                               3.162277660f, 1.333521432f, 0.562341325f, 0.237137371f};
        short8 sh, sl, ch, cl;
        #pragma unroll
        for (int f = 0; f < 8; ++f) {
            float s, c;
            __sincosf(posv * w100[f], &s, &c);
            s = fmaxf(s, 0.f);
            c = fmaxf(c, 0.f);
            unsigned short hs = f32_bf16_rne(s);
            unsigned short hc = f32_bf16_rne(c);
            sh[f] = (short)hs; sl[f] = (short)f32_bf16_rne(s - bf16_f32(hs));
            ch[f] = (short)hc; cl[f] = (short)f32_bf16_rne(c - bf16_f32(hc));
        }
        *(short8*)&AsH[pl * 72 + p * 16]     = sh;
        *(short8*)&AsH[pl * 72 + p * 16 + 8] = ch;
        *(short8*)&AsL[pl * 72 + p * 16]     = sl;
        *(short8*)&AsL[pl * 72 + p * 16 + 8] = cl;
    }
    __syncthreads();

    const int lane = tid & 63;
    const int w = tid >> 6;
    const int m = lane & 15;
    const int quad = lane >> 4;
    const unsigned short* apH = &AsH[(w * 16 + m) * 72 + quad * 8];
    const unsigned short* apL = &AsL[(w * 16 + m) * 72 + quad * 8];
    const unsigned short* bpH = &BsH[m * 72 + quad * 8];
    const unsigned short* bpL = &BsL[m * 72 + quad * 8];
    floatx4 acc = {0.f, 0.f, 0.f, 0.f};
    acc = mfma16(*(const short8*)apH,        *(const short8*)bpH,        acc);
    acc = mfma16(*(const short8*)(apH + 32), *(const short8*)(bpH + 32), acc);
    acc = mfma16(*(const short8*)apH,        *(const short8*)bpL,        acc);
    acc = mfma16(*(const short8*)(apH + 32), *(const short8*)(bpL + 32), acc);
    acc = mfma16(*(const short8*)apL,        *(const short8*)bpH,        acc);
    acc = mfma16(*(const short8*)(apL + 32), *(const short8*)(bpH + 32), acc);

    const float bpv = b_pos[m];
    #pragma unroll
    for (int r = 0; r < 4; ++r)
        stg[m * 68 + w * 16 + quad * 4 + r] = (_Float16)__logf(fmaxf(acc[r] + bpv, 1e-6f));
    __syncthreads();
    // coalesced-per-plane store: 4 planes/wave, 128B runs
    const int g2 = tid >> 4, c16 = tid & 15;
    *(half4*)(out + (long long)g2 * 524288 + pbase + c16 * 4) =
        *(const half4*)&stg[g2 * 68 + c16 * 4];
}

// ---------------------------------------------------------------------------
// Fused scores + bias + softmax + output GEMM. Block = (g, 16 A-rows).
// All qk/vt loads coalesced via fragment-packed layout, depth-2 prefetch.
// Bias slice staged into LDS (aliases wpack). Output via LDS -> float4 stores.
// ---------------------------------------------------------------------------
template <int NC>
__device__ __forceinline__ void attn_body(
    int g, int bx,
    const unsigned short* __restrict__ qk, int pA, int pB0,
    const _Float16* __restrict__ bias,
    const unsigned short* __restrict__ vt, int cc0,
    const float* __restrict__ b_conv, float* __restrict__ outp,
    unsigned short* wpack, float* redA, float* redB)
{
    constexpr int NCOL = NC * 64;
    constexpr int WS = NCOL + 8;
    constexpr int SHIFT = (NC == 16) ? 10 : 9;

    const int bm = bx * 16;
    const int tid = threadIdx.x;
    const int lane = tid & 63;
    const int w = tid >> 6;
    const int m = lane & 15;
    const int quad = lane >> 4;

    // ---- stage bias slice (16 x NCOL fp16) into LDS, coalesced 16B loads
    _Float16* bb = (_Float16*)wpack;
    {
        const _Float16* bsrc = bias + (long long)g * 524288 + (long long)bm * NCOL;
        #pragma unroll
        for (int i = 0; i < (16 * NCOL) / (256 * 8); ++i) {
            const int idx = (i * 256 + tid) * 8;
            const int row = idx >> SHIFT;
            const int col = idx & (NCOL - 1);
            *(int4*)(bb + row * WS + col) = *(const int4*)(bsrc + idx);
        }
    }

    // A-fragments: packed, coalesced
    const unsigned short* abase = qk + ((long long)(g * 96 + pA)) * 1024;
    short8 aq0 = *(const short8*)(abase + lane * 8);
    short8 aq1 = *(const short8*)(abase + 512 + lane * 8);

    // B chunks: p = pB0 + c*4 + w  -> stride 4096 shorts per chunk
    const unsigned short* bptr = qk + ((long long)(g * 96 + pB0 + w)) * 1024 + lane * 8;
    short8 B0[2], B1[2];
    B0[0] = *(const short8*)bptr;
    B1[0] = *(const short8*)(bptr + 512);
    B0[1] = *(const short8*)(bptr + 4096);
    B1[1] = *(const short8*)(bptr + 4096 + 512);

    __syncthreads();   // bias staged

    const _Float16* brow = bb + (quad * 4) * WS + w * 16 + m;

    float v[NC][4];
    #pragma unroll
    for (int c = 0; c < NC; ++c) {
        float bv[4];
        #pragma unroll
        for (int r = 0; r < 4; ++r)
            bv[r] = (float)brow[r * WS + c * 64];
        floatx4 acc = {0.f, 0.f, 0.f, 0.f};
        acc = mfma16(aq0, B0[c & 1], acc);
        acc = mfma16(aq1, B1[c & 1], acc);
        if (c + 2 < NC) {
            const unsigned short* nb = bptr + (long long)(c + 2) * 4096;
            B0[c & 1] = *(const short8*)nb;
            B1[c & 1] = *(const short8*)(nb + 512);
        }
        #pragma unroll
        for (int r = 0; r < 4; ++r)
            v[c][r] = fmaf(0.125f, acc[r], bv[r]);
    }

    // prefetch vt chunks 0,1 (coalesced) — overlaps softmax
    const unsigned short* vptr = vt + ((long long)(g * 24 + cc0)) * 4096
                               + w * 1024 + lane * 8;
    short8 V0[2], V1[2];
    V0[0] = *(const short8*)vptr;
    V1[0] = *(const short8*)(vptr + 512);
    V0[1] = *(const short8*)(vptr + 4096);
    V1[1] = *(const short8*)(vptr + 4096 + 512);

    // ---- softmax over rows (row = quad*4+r)
    float rmax[4];
    #pragma unroll
    for (int r = 0; r < 4; ++r) {
        float mx = v[0][r];
        #pragma unroll
        for (int c = 1; c < NC; ++c) mx = fmaxf(mx, v[c][r]);
        #pragma unroll
        for (int off = 1; off < 16; off <<= 1)
            mx = fmaxf(mx, __shfl_xor(mx, off, 64));
        rmax[r] = mx;
    }
    if (m == 0) {
        #pragma unroll
        for (int r = 0; r < 4; ++r) redA[w * 16 + quad * 4 + r] = rmax[r];
    }
    __syncthreads();
    #pragma unroll
    for (int r = 0; r < 4; ++r)
        rmax[r] = fmaxf(fmaxf(redA[quad*4+r], redA[16 + quad*4+r]),
                        fmaxf(redA[32 + quad*4+r], redA[48 + quad*4+r]));

    float rsum[4] = {0.f, 0.f, 0.f, 0.f};
    #pragma unroll
    for (int c = 0; c < NC; ++c)
        #pragma unroll
        for (int r = 0; r < 4; ++r) {
            v[c][r] = __expf(v[c][r] - rmax[r]);
            rsum[r] += v[c][r];
        }
    #pragma unroll
    for (int r = 0; r < 4; ++r)
        #pragma unroll
        for (int off = 1; off < 16; off <<= 1)
            rsum[r] += __shfl_xor(rsum[r], off, 64);
    if (m == 0) {
        #pragma unroll
        for (int r = 0; r < 4; ++r) redB[w * 16 + quad * 4 + r] = rsum[r];
    }
    __syncthreads();   // all bias reads complete before wpack overwrite
    float rinv[4];
    #pragma unroll
    for (int r = 0; r < 4; ++r)
        rinv[r] = 1.f / (redB[quad*4+r] + redB[16 + quad*4+r] +
                         redB[32 + quad*4+r] + redB[48 + quad*4+r]);

    #pragma unroll
    for (int c = 0; c < NC; ++c)
        #pragma unroll
        for (int r = 0; r < 4; ++r)
            wpack[(quad * 4 + r) * WS + c * 64 + w * 16 + m] =
                f32_bf16_rne(v[c][r] * rinv[r]);

    __syncthreads();   // wpack visible

    // ---- phase 3: out = W @ vt^T (vt packed, coalesced, depth-2)
    floatx4 oacc = {0.f, 0.f, 0.f, 0.f};
    const unsigned short* awp = wpack + m * WS + quad * 8;
    #pragma unroll
    for (int kc = 0; kc < NC; ++kc) {
        short8 a0 = *(const short8*)(awp + kc * 64);
        short8 a1 = *(const short8*)(awp + kc * 64 + 32);
        oacc = mfma16(a0, V0[kc & 1], oacc);
        oacc = mfma16(a1, V1[kc & 1], oacc);
        if (kc + 2 < NC) {
            const unsigned short* nv = vptr + (long long)(kc + 2) * 4096;
            V0[kc & 1] = *(const short8*)nv;
            V1[kc & 1] = *(const short8*)(nv + 512);
        }
    }

    // ---- output via LDS -> coalesced float4 stores
    const int o = w * 16 + m;
    const float bc = b_conv[g * 64 + o];
    __syncthreads();   // wpack weight reads done
    float* ot = (float*)wpack;         // 16 x 68 floats
    #pragma unroll
    for (int r = 0; r < 4; ++r)
        ot[(quad * 4 + r) * 68 + o] = oacc[r] + bc;
    __syncthreads();
    const int orow = tid >> 4, oc4 = (tid & 15) * 4;
    float4 ov = *(const float4*)&ot[orow * 68 + oc4];
    *(float4*)(outp + (long long)(bm + orow) * 1024 + g * 64 + oc4) = ov;
}

// Flat grid, 1536 blocks: [0,512) gt (g = bx>>5, rb = bx&31),
// [512,1536) ctx (g = (bx-512)>>6, rb = (bx-512)&63).
__global__ __launch_bounds__(256) void attn_out_kernel(
    const unsigned short* __restrict__ qk_pack,
    const _Float16* __restrict__ bias_gt, const _Float16* __restrict__ bias_ctx,
    const unsigned short* __restrict__ vt_pack, const float* __restrict__ b_conv,
    float* __restrict__ out_gt, float* __restrict__ out_ctx)
{
    __shared__ __align__(16) unsigned short wpack[16 * 1032];
    __shared__ float redA[64], redB[64];

    const int bx = blockIdx.x;
    if (bx < 512) {
        const int rb = bx & 31;
        attn_body<16>(bx >> 5, rb, qk_pack, /*pA=*/rb, /*pB0=*/32,
                      bias_gt, vt_pack, /*cc0=*/8, b_conv, out_gt,
                      wpack, redA, redB);
    } else {
        const int b2 = bx - 512;
        const int rb = b2 & 63;
        attn_body<8>(b2 >> 6, rb, qk_pack, /*pA=*/32 + rb, /*pB0=*/0,
                     bias_ctx, vt_pack, /*cc0=*/0, b_conv, out_ctx,
                     wpack, redA, redB);
    }
}

// ---------------------------------------------------------------------------
extern "C" void kernel_launch(void* const* d_in, const int* in_sizes, int n_in,
                              void* d_out, int out_size, void* d_ws, size_t ws_size,
                              hipStream_t stream)
{
    const float* feat     = (const float*)d_in[0];
    const float* ctx_feat = (const float*)d_in[1];
    const float* box      = (const float*)d_in[2];
    const float* ctx_box  = (const float*)d_in[3];
    const float* w_fc_gt  = (const float*)d_in[4];
    const float* b_fc_gt  = (const float*)d_in[5];
    const float* w_fc_ctx = (const float*)d_in[6];
    const float* b_fc_ctx = (const float*)d_in[7];
    const float* w_pos_gt = (const float*)d_in[8];
    const float* b_pos_gt = (const float*)d_in[9];
    const float* w_pos_ctx= (const float*)d_in[10];
    const float* b_pos_ctx= (const float*)d_in[11];
    const float* w_conv   = (const float*)d_in[12];
    const float* b_conv   = (const float*)d_in[13];

    float* ws = (float*)d_ws;
    unsigned short* in_bf   = (unsigned short*)ws;           // 1572864 s
    unsigned short* ctx_bf  = in_bf + 524288LL;
    unsigned short* qk_pack = in_bf + 1572864LL;             // 1572864 s
    _Float16* bias_gt  = (_Float16*)(ws + 1572864LL);        // 8388608 h
    _Float16* bias_ctx = (_Float16*)(ws + 5767168LL);        // 8388608 h
    unsigned short* wconv_bf = (unsigned short*)(ws + 9961472LL);   // 1048576 s
    unsigned short* vt_pack  = (unsigned short*)(ws + 10485760LL);  // 1572864 s
    unsigned short* wfcgt_bf = (unsigned short*)(ws + 11272192LL);  // 1048576 s
    unsigned short* wfcctx_bf= wfcgt_bf + 1048576LL;                // 1048576 s

    float* out_gt  = (float*)d_out;
    float* out_ctx = (float*)d_out + 524288LL;

    // 1) merged casts + position bias
    hipLaunchKernelGGL(prep_kernel, dim3(21504), dim3(256), 0, stream,
                       box, ctx_box, w_pos_gt, b_pos_gt, w_pos_ctx, b_pos_ctx,
                       bias_gt, bias_ctx,
                       feat, in_bf, 524288,
                       ctx_feat, ctx_bf, 1048576,
                       w_fc_gt, wfcgt_bf, 1048576,
                       w_fc_ctx, wfcctx_bf, 1048576,
                       w_conv, wconv_bf, 1048576);

    // 2) merged q/k projection + v-projection, fragment-packed output
    hipLaunchKernelGGL(projvt_kernel, dim3(24, 16, 2), dim3(256), 0, stream,
                       in_bf, wfcgt_bf, wfcctx_bf, b_fc_gt, b_fc_ctx, qk_pack,
                       wconv_bf, vt_pack);

    // 3) fused scores+softmax+output, both directions
    hipLaunchKernelGGL(attn_out_kernel, dim3(1536), dim3(256), 0, stream,
                       qk_pack, bias_gt, bias_ctx, vt_pack, b_conv, out_gt, out_ctx);
}

// Round 11
// 156.568 us; speedup vs baseline: 1.1506x; 1.0106x over previous
//
#include <hip/hip_runtime.h>
#include <math.h>

// M=512, N=1024, G=16, D=64, C=1024. All GEMM-shaped work on bf16 MFMA 16x16x32.
// pos_bias uses a bf16 hi/lo split MFMA (rounds 4/6: plain bf16 dot error
// ~2e-4 sign-flips entries in log-clip floor rows -> absmax 0.205).
//
// Round 11: prep was 49us pure-VALU (74% busy) — the RNE hi/lo conversion
// arithmetic (~450 cyc/wave, model-verified). Fixes:
//  (a) truncation split (bit-mask hi, bit-mask lo of residual), packed 2-at-a-
//      time into ints: ~10 ops/2 values vs ~24, no element-insertion cost.
//      Residual 3e-6 -> 6e-6, still 8x under the 4.7e-5 floor-row requirement.
//  (b) A-fragments built directly in registers (r4 structure — functionally
//      verified by r4==r6 bit-identical outputs; precision now fixed by hi/lo).
//      Kills AsH/AsL LDS round trip + barrier + 2.2M bank conflicts.
//  (c) cos(t)=sin(t+pi/2), lane-fixed phase: single-trans per value.
//
// Pipeline (3 launches): prep (casts + pos_bias) -> projvt (packed) -> attn_out.
//
// qk_pack[g][p][part][lane][8shorts]: X[row][col], row=p*16+(lane&15),
// col=part*32+(lane>>4)*8+j (g-slice base g*64); p: q rows p=row>>4 (0..31),
// k rows 32+(row-512)>>4 (32..95). vt_pack[g][cc][p][part][lane][8]: p=o>>4.
//
// Workspace (float offsets), total 12,320,768 floats = 49.3 MB:
//   [0,1572864)        : shorts: in_bf (feat 524288 + ctx 1048576), qk_pack (1572864)
//   [1572864,5767168)  : bias_gt  fp16 (16,512,1024)
//   [5767168,9961472)  : bias_ctx fp16 (16,1024,512)
//   [9961472,10485760) : wconv_bf (1048576 s)
//   [10485760,11272192): vt_pack (1572864 s)
//   [11272192,12320768): wfcgt_bf + wfcctx_bf

typedef __attribute__((ext_vector_type(8))) short short8;   // 8 bf16 = 4 VGPRs
typedef __attribute__((ext_vector_type(4))) float floatx4;
typedef __attribute__((ext_vector_type(4))) _Float16 half4;
typedef __attribute__((ext_vector_type(4))) unsigned uint4v;

__device__ inline unsigned short f32_bf16_rne(float x) {
    union { float f; unsigned u; } v; v.f = x;
    unsigned u = v.u;
    return (unsigned short)((u + 0x7fffu + ((u >> 16) & 1u)) >> 16);
}

__device__ inline unsigned fbits(float x) {
    union { float f; unsigned u; } v; v.f = x; return v.u;
}
__device__ inline float bitsf(unsigned u) {
    union { unsigned u; float f; } v; v.u = u; return v.f;
}

__device__ __forceinline__ floatx4 mfma16(short8 a, short8 b, floatx4 c) {
    return __builtin_amdgcn_mfma_f32_16x16x32_bf16(a, b, c, 0, 0, 0);
}

// ---------------------------------------------------------------------------
// 64x64 tile NT bf16 GEMM core with FRAGMENT-PACKED output (r10, verified).
// ---------------------------------------------------------------------------
__device__ __forceinline__ void gemm_tile_pack(
    const unsigned short* __restrict__ Ab, int lda,
    const unsigned short* __restrict__ Bb, int ldb, int K,
    unsigned short* __restrict__ out_base,
    const float* __restrict__ biasvec,
    unsigned short* As, unsigned short* Bs)
{
    const int tid = threadIdx.x;
    const int lr = tid >> 3;          // 0..31 (8 lanes/row)
    const int lk = (tid & 7) * 8;     // 0..56
    const int lane = tid & 63;
    const int wave = tid >> 6;
    const int qr = (wave >> 1) * 32;
    const int qc = (wave & 1) * 32;
    const int m = lane & 15;
    const int quad = lane >> 4;

    const unsigned short* Ap  = Ab + (long long)lr * lda + lk;
    const unsigned short* Ap2 = Ap + 32LL * lda;
    const unsigned short* Bp  = Bb + (long long)lr * ldb + lk;
    const unsigned short* Bp2 = Bp + 32LL * ldb;
    unsigned short* AsW  = As + lr * 72 + lk;
    unsigned short* AsW2 = As + (lr + 32) * 72 + lk;
    unsigned short* BsW  = Bs + lr * 72 + lk;
    unsigned short* BsW2 = Bs + (lr + 32) * 72 + lk;
    const unsigned short* a0p = As + (qr + m) * 72 + quad * 8;
    const unsigned short* b0p = Bs + (qc + m) * 72 + quad * 8;

    floatx4 acc00 = {0.f,0.f,0.f,0.f}, acc01 = {0.f,0.f,0.f,0.f};
    floatx4 acc10 = {0.f,0.f,0.f,0.f}, acc11 = {0.f,0.f,0.f,0.f};

    int4 pa0 = *(const int4*)Ap;
    int4 pa1 = *(const int4*)Ap2;
    int4 pb0 = *(const int4*)Bp;
    int4 pb1 = *(const int4*)Bp2;
    int4 qa0 = *(const int4*)(Ap + 64);
    int4 qa1 = *(const int4*)(Ap2 + 64);
    int4 qb0 = *(const int4*)(Bp + 64);
    int4 qb1 = *(const int4*)(Bp2 + 64);

    for (int k0 = 0; ; ) {
        __syncthreads();
        *(int4*)AsW  = pa0;
        *(int4*)AsW2 = pa1;
        *(int4*)BsW  = pb0;
        *(int4*)BsW2 = pb1;
        __syncthreads();
        pa0 = qa0; pa1 = qa1; pb0 = qb0; pb1 = qb1;
        const int kf = k0 + 128;
        if (kf < K) {
            qa0 = *(const int4*)(Ap + kf);
            qa1 = *(const int4*)(Ap2 + kf);
            qb0 = *(const int4*)(Bp + kf);
            qb1 = *(const int4*)(Bp2 + kf);
        }
        #pragma unroll
        for (int kk = 0; kk < 64; kk += 32) {
            short8 a0 = *(const short8*)(a0p + kk);
            short8 a1 = *(const short8*)(a0p + 16 * 72 + kk);
            short8 b0 = *(const short8*)(b0p + kk);
            short8 b1 = *(const short8*)(b0p + 16 * 72 + kk);
            acc00 = mfma16(a0, b0, acc00);
            acc01 = mfma16(a0, b1, acc01);
            acc10 = mfma16(a1, b0, acc10);
            acc11 = mfma16(a1, b1, acc11);
        }
        k0 += 64;
        if (k0 >= K) break;
    }

    float bias0 = 0.f, bias1 = 0.f;
    if (biasvec) { bias0 = biasvec[qc + m]; bias1 = biasvec[qc + 16 + m]; }

    __syncthreads();
    const floatx4 accs[2][2] = { {acc00, acc01}, {acc10, acc11} };
    #pragma unroll
    for (int i = 0; i < 2; ++i)
        #pragma unroll
        for (int r = 0; r < 4; ++r) {
            const int lrow = qr + i * 16 + quad * 4 + r;
            #pragma unroll
            for (int j = 0; j < 2; ++j) {
                const int lcol = qc + j * 16 + m;
                float val = accs[i][j][r] + (j ? bias1 : bias0);
                As[lrow * 72 + lcol] = f32_bf16_rne(val);
            }
        }
    __syncthreads();
    #pragma unroll
    for (int h = 0; h < 2; ++h) {
        const int f = h * 2048 + tid * 8;
        const int lanep = (f >> 3) & 63;
        const int part = (f >> 9) & 1;
        const int ploc = f >> 10;
        const int row = ploc * 16 + (lanep & 15);
        const int col = part * 32 + ((lanep >> 4) << 3);
        short8 v8 = *(const short8*)&As[row * 72 + col];
        *(short8*)(out_base + f) = v8;
    }
}

// ---------------------------------------------------------------------------
__global__ __launch_bounds__(256) void projvt_kernel(
    const unsigned short* __restrict__ in_bf, const unsigned short* __restrict__ wgt,
    const unsigned short* __restrict__ wctx,
    const float* __restrict__ bgt, const float* __restrict__ bctx,
    unsigned short* __restrict__ qk_pack,
    const unsigned short* __restrict__ wconv, unsigned short* __restrict__ vt_pack)
{
    __shared__ __align__(16) unsigned short As[64 * 72];
    __shared__ __align__(16) unsigned short Bs[64 * 72];
    if (blockIdx.z == 0) {
        const int bm = blockIdx.x * 64;
        const int g = blockIdx.y;
        const unsigned short* B = (bm < 512) ? wgt : wctx;
        const float* bias = (bm < 512) ? bgt : bctx;
        gemm_tile_pack(in_bf + (long long)bm * 1024, 1024,
                       B + (long long)g * 65536, 1024, 1024,
                       qk_pack + ((long long)g * 96 + blockIdx.x * 4) * 1024,
                       bias + g * 64, As, Bs);
    } else {
        const int cc = blockIdx.x;       // 0..23
        const int g = blockIdx.y;
        gemm_tile_pack(wconv + (long long)g * 65536, 1024,
                       in_bf + (long long)cc * 65536, 1024, 1024,
                       vt_pack + ((long long)g * 24 + cc) * 4096,
                       nullptr, As, Bs);
    }
}

// ---------------------------------------------------------------------------
// Merged prep: blocks [0,16384) = pos_bias, [16384,21504) = fp32->bf16 casts.
// pos_bias: direct in-register A-fragments (trunc hi/lo split, packed),
// LDS-staged B hi/lo, 6x MFMA, log -> fp16 planes via LDS -> coalesced store.
// ---------------------------------------------------------------------------
__global__ __launch_bounds__(256) void prep_kernel(
    const float* __restrict__ box, const float* __restrict__ ctx_box,
    const float* __restrict__ w_gt, const float* __restrict__ b_gt,
    const float* __restrict__ w_ctx, const float* __restrict__ b_ctx,
    _Float16* __restrict__ bias_gt, _Float16* __restrict__ bias_ctx,
    const float* s0, unsigned short* d0, int n0,
    const float* s1, unsigned short* d1, int n1,
    const float* s2, unsigned short* d2, int n2,
    const float* s3, unsigned short* d3, int n3,
    const float* s4, unsigned short* d4, int n4)
{
    const int bx = blockIdx.x;
    if (bx >= 16384) {                   // -------- cast branch
        const int bc = bx - 16384;
        const int which = bc >> 10;
        const int xb = bc & 1023;
        const float* s; unsigned short* d; int n;
        switch (which) {
            case 0: s = s0; d = d0; n = n0; break;
            case 1: s = s1; d = d1; n = n1; break;
            case 2: s = s2; d = d2; n = n2; break;
            case 3: s = s3; d = d3; n = n3; break;
            default: s = s4; d = d4; n = n4; break;
        }
        int idx = (xb * 256 + threadIdx.x) * 4;
        if (idx < n) {
            float4 v = *(const float4*)(s + idx);
            ushort4 o;
            o.x = f32_bf16_rne(v.x); o.y = f32_bf16_rne(v.y);
            o.z = f32_bf16_rne(v.z); o.w = f32_bf16_rne(v.w);
            *(ushort4*)(d + idx) = o;
        }
        return;
    }

    // -------- pos_bias branch
    const bool first = (bx < 8192);
    const long long blk = first ? bx : (bx - 8192);
    const float* boxA = first ? box : ctx_box;
    const float* boxB = first ? ctx_box : box;
    const float* w_pos = first ? w_gt : w_ctx;
    const float* b_pos = first ? b_gt : b_ctx;
    _Float16* out = first ? bias_gt : bias_ctx;
    const int shift = first ? 10 : 9;

    __shared__ __align__(16) unsigned short BsH[16 * 72];
    __shared__ __align__(16) unsigned short BsL[16 * 72];
    __shared__ _Float16 stg[16 * 68];

    const int tid = threadIdx.x;

    {   // stage B: w_pos (16x64 fp32) -> bf16 hi + lo (trunc split, packed)
        const int g = tid >> 4;
        const int d = (tid & 15) * 4;
        float4 wv = *(const float4*)(w_pos + g * 64 + d);
        unsigned u0 = fbits(wv.x), u1 = fbits(wv.y);
        unsigned u2 = fbits(wv.z), u3 = fbits(wv.w);
        unsigned r0 = fbits(wv.x - bitsf(u0 & 0xFFFF0000u));
        unsigned r1 = fbits(wv.y - bitsf(u1 & 0xFFFF0000u));
        unsigned r2 = fbits(wv.z - bitsf(u2 & 0xFFFF0000u));
        unsigned r3 = fbits(wv.w - bitsf(u3 & 0xFFFF0000u));
        uint2 hv, lv;
        hv.x = (u0 >> 16) | (u1 & 0xFFFF0000u);
        hv.y = (u2 >> 16) | (u3 & 0xFFFF0000u);
        lv.x = (r0 >> 16) | (r1 & 0xFFFF0000u);
        lv.y = (r2 >> 16) | (r3 & 0xFFFF0000u);
        *(uint2*)&BsH[g * 72 + d] = hv;
        *(uint2*)&BsL[g * 72 + d] = lv;
    }
    __syncthreads();

    const int lane = tid & 63;
    const int w = tid >> 6;
    const int m = lane & 15;
    const int quad = lane >> 4;
    const long long pbase = blk * 64;

    // A-fragments direct in registers. Lane (m,quad) of wave w holds A row
    // m (pair pbase + w*16 + m), dims quad*8+jj (chunk0) and 32+quad*8+jj
    // (chunk1): p = quad>>1 (+2 for chunk1), sin if quad even else cos (f=jj).
    const long long pair = pbase + w * 16 + m;
    const int i = (int)(pair >> shift);
    const int j = (int)(pair & ((1 << shift) - 1));
    float4 ba = *(const float4*)(boxA + i * 4);
    float4 bb = *(const float4*)(boxB + j * 4);
    float bw = ba.z - ba.x + 1.f, bh = ba.w - ba.y + 1.f;
    float cx = 0.5f * (ba.x + ba.z), cy = 0.5f * (ba.y + ba.w);
    float cbw = bb.z - bb.x + 1.f, cbh = bb.w - bb.y + 1.f;
    float ccx = 0.5f * (bb.x + bb.z), ccy = 0.5f * (bb.y + bb.w);
    const bool qlow = (quad < 2);
    float arg_lo = qlow ? fmaxf(fabsf((cx - ccx) / bw), 1e-3f)
                        : fmaxf(fabsf((cy - ccy) / bh), 1e-3f);
    float arg_hi = qlow ? (cbw / bw) : (cbh / bh);
    float pos_lo = __logf(arg_lo);
    float pos_hi = __logf(arg_hi);
    const float phase = (quad & 1) ? 1.57079632679f : 0.0f;  // cos(t)=sin(t+pi/2)

    const float w100[8] = {100.f, 42.169650342f, 17.782794100f, 7.498942093f,
                           3.162277660f, 1.333521432f, 0.562341325f, 0.237137371f};
    unsigned hp0[4], lp0[4], hp1[4], lp1[4];
    #pragma unroll
    for (int fi = 0; fi < 4; ++fi) {
        float x0 = fmaxf(__sinf(fmaf(w100[2*fi],     pos_lo, phase)), 0.f);
        float x1 = fmaxf(__sinf(fmaf(w100[2*fi + 1], pos_lo, phase)), 0.f);
        unsigned u0 = fbits(x0), u1 = fbits(x1);
        unsigned r0 = fbits(x0 - bitsf(u0 & 0xFFFF0000u));
        unsigned r1 = fbits(x1 - bitsf(u1 & 0xFFFF0000u));
        hp0[fi] = (u0 >> 16) | (u1 & 0xFFFF0000u);
        lp0[fi] = (r0 >> 16) | (r1 & 0xFFFF0000u);
        float y0 = fmaxf(__sinf(fmaf(w100[2*fi],     pos_hi, phase)), 0.f);
        float y1 = fmaxf(__sinf(fmaf(w100[2*fi + 1], pos_hi, phase)), 0.f);
        unsigned v0 = fbits(y0), v1 = fbits(y1);
        unsigned s0r = fbits(y0 - bitsf(v0 & 0xFFFF0000u));
        unsigned s1r = fbits(y1 - bitsf(v1 & 0xFFFF0000u));
        hp1[fi] = (v0 >> 16) | (v1 & 0xFFFF0000u);
        lp1[fi] = (s0r >> 16) | (s1r & 0xFFFF0000u);
    }
    union { uint4v u; short8 s; } cH0, cL0, cH1, cL1;
    cH0.u = (uint4v){hp0[0], hp0[1], hp0[2], hp0[3]};
    cL0.u = (uint4v){lp0[0], lp0[1], lp0[2], lp0[3]};
    cH1.u = (uint4v){hp1[0], hp1[1], hp1[2], hp1[3]};
    cL1.u = (uint4v){lp1[0], lp1[1], lp1[2], lp1[3]};

    const unsigned short* bpH = &BsH[m * 72 + quad * 8];
    const unsigned short* bpL = &BsL[m * 72 + quad * 8];
    short8 bH0 = *(const short8*)bpH;
    short8 bH1 = *(const short8*)(bpH + 32);
    short8 bL0 = *(const short8*)bpL;
    short8 bL1 = *(const short8*)(bpL + 32);

    floatx4 acc = {0.f, 0.f, 0.f, 0.f};
    acc = mfma16(cH0.s, bH0, acc);
    acc = mfma16(cH1.s, bH1, acc);
    acc = mfma16(cH0.s, bL0, acc);
    acc = mfma16(cH1.s, bL1, acc);
    acc = mfma16(cL0.s, bH0, acc);
    acc = mfma16(cL1.s, bH1, acc);

    // C: row = pair-local w*16 + quad*4 + r, col = group m
    const float bpv = b_pos[m];
    #pragma unroll
    for (int r = 0; r < 4; ++r)
        stg[m * 68 + w * 16 + quad * 4 + r] = (_Float16)__logf(fmaxf(acc[r] + bpv, 1e-6f));
    __syncthreads();
    const int g2 = tid >> 4, c16 = tid & 15;
    *(half4*)(out + (long long)g2 * 524288 + pbase + c16 * 4) =
        *(const half4*)&stg[g2 * 68 + c16 * 4];
}

// ---------------------------------------------------------------------------
// Fused scores + bias + softmax + output GEMM (r10, verified).
// ---------------------------------------------------------------------------
template <int NC>
__device__ __forceinline__ void attn_body(
    int g, int bx,
    const unsigned short* __restrict__ qk, int pA, int pB0,
    const _Float16* __restrict__ bias,
    const unsigned short* __restrict__ vt, int cc0,
    const float* __restrict__ b_conv, float* __restrict__ outp,
    unsigned short* wpack, float* redA, float* redB)
{
    constexpr int NCOL = NC * 64;
    constexpr int WS = NCOL + 8;
    constexpr int SHIFT = (NC == 16) ? 10 : 9;

    const int bm = bx * 16;
    const int tid = threadIdx.x;
    const int lane = tid & 63;
    const int w = tid >> 6;
    const int m = lane & 15;
    const int quad = lane >> 4;

    _Float16* bb = (_Float16*)wpack;
    {
        const _Float16* bsrc = bias + (long long)g * 524288 + (long long)bm * NCOL;
        #pragma unroll
        for (int i = 0; i < (16 * NCOL) / (256 * 8); ++i) {
            const int idx = (i * 256 + tid) * 8;
            const int row = idx >> SHIFT;
            const int col = idx & (NCOL - 1);
            *(int4*)(bb + row * WS + col) = *(const int4*)(bsrc + idx);
        }
    }

    const unsigned short* abase = qk + ((long long)(g * 96 + pA)) * 1024;
    short8 aq0 = *(const short8*)(abase + lane * 8);
    short8 aq1 = *(const short8*)(abase + 512 + lane * 8);

    const unsigned short* bptr = qk + ((long long)(g * 96 + pB0 + w)) * 1024 + lane * 8;
    short8 B0[2], B1[2];
    B0[0] = *(const short8*)bptr;
    B1[0] = *(const short8*)(bptr + 512);
    B0[1] = *(const short8*)(bptr + 4096);
    B1[1] = *(const short8*)(bptr + 4096 + 512);

    __syncthreads();   // bias staged

    const _Float16* brow = bb + (quad * 4) * WS + w * 16 + m;

    float v[NC][4];
    #pragma unroll
    for (int c = 0; c < NC; ++c) {
        float bv[4];
        #pragma unroll
        for (int r = 0; r < 4; ++r)
            bv[r] = (float)brow[r * WS + c * 64];
        floatx4 acc = {0.f, 0.f, 0.f, 0.f};
        acc = mfma16(aq0, B0[c & 1], acc);
        acc = mfma16(aq1, B1[c & 1], acc);
        if (c + 2 < NC) {
            const unsigned short* nb = bptr + (long long)(c + 2) * 4096;
            B0[c & 1] = *(const short8*)nb;
            B1[c & 1] = *(const short8*)(nb + 512);
        }
        #pragma unroll
        for (int r = 0; r < 4; ++r)
            v[c][r] = fmaf(0.125f, acc[r], bv[r]);
    }

    const unsigned short* vptr = vt + ((long long)(g * 24 + cc0)) * 4096
                               + w * 1024 + lane * 8;
    short8 V0[2], V1[2];
    V0[0] = *(const short8*)vptr;
    V1[0] = *(const short8*)(vptr + 512);
    V0[1] = *(const short8*)(vptr + 4096);
    V1[1] = *(const short8*)(vptr + 4096 + 512);

    float rmax[4];
    #pragma unroll
    for (int r = 0; r < 4; ++r) {
        float mx = v[0][r];
        #pragma unroll
        for (int c = 1; c < NC; ++c) mx = fmaxf(mx, v[c][r]);
        #pragma unroll
        for (int off = 1; off < 16; off <<= 1)
            mx = fmaxf(mx, __shfl_xor(mx, off, 64));
        rmax[r] = mx;
    }
    if (m == 0) {
        #pragma unroll
        for (int r = 0; r < 4; ++r) redA[w * 16 + quad * 4 + r] = rmax[r];
    }
    __syncthreads();
    #pragma unroll
    for (int r = 0; r < 4; ++r)
        rmax[r] = fmaxf(fmaxf(redA[quad*4+r], redA[16 + quad*4+r]),
                        fmaxf(redA[32 + quad*4+r], redA[48 + quad*4+r]));

    float rsum[4] = {0.f, 0.f, 0.f, 0.f};
    #pragma unroll
    for (int c = 0; c < NC; ++c)
        #pragma unroll
        for (int r = 0; r < 4; ++r) {
            v[c][r] = __expf(v[c][r] - rmax[r]);
            rsum[r] += v[c][r];
        }
    #pragma unroll
    for (int r = 0; r < 4; ++r)
        #pragma unroll
        for (int off = 1; off < 16; off <<= 1)
            rsum[r] += __shfl_xor(rsum[r], off, 64);
    if (m == 0) {
        #pragma unroll
        for (int r = 0; r < 4; ++r) redB[w * 16 + quad * 4 + r] = rsum[r];
    }
    __syncthreads();   // all bias reads complete before wpack overwrite
    float rinv[4];
    #pragma unroll
    for (int r = 0; r < 4; ++r)
        rinv[r] = 1.f / (redB[quad*4+r] + redB[16 + quad*4+r] +
                         redB[32 + quad*4+r] + redB[48 + quad*4+r]);

    #pragma unroll
    for (int c = 0; c < NC; ++c)
        #pragma unroll
        for (int r = 0; r < 4; ++r)
            wpack[(quad * 4 + r) * WS + c * 64 + w * 16 + m] =
                f32_bf16_rne(v[c][r] * rinv[r]);

    __syncthreads();   // wpack visible

    floatx4 oacc = {0.f, 0.f, 0.f, 0.f};
    const unsigned short* awp = wpack + m * WS + quad * 8;
    #pragma unroll
    for (int kc = 0; kc < NC; ++kc) {
        short8 a0 = *(const short8*)(awp + kc * 64);
        short8 a1 = *(const short8*)(awp + kc * 64 + 32);
        oacc = mfma16(a0, V0[kc & 1], oacc);
        oacc = mfma16(a1, V1[kc & 1], oacc);
        if (kc + 2 < NC) {
            const unsigned short* nv = vptr + (long long)(kc + 2) * 4096;
            V0[kc & 1] = *(const short8*)nv;
            V1[kc & 1] = *(const short8*)(nv + 512);
        }
    }

    const int o = w * 16 + m;
    const float bc = b_conv[g * 64 + o];
    __syncthreads();   // wpack weight reads done
    float* ot = (float*)wpack;         // 16 x 68 floats
    #pragma unroll
    for (int r = 0; r < 4; ++r)
        ot[(quad * 4 + r) * 68 + o] = oacc[r] + bc;
    __syncthreads();
    const int orow = tid >> 4, oc4 = (tid & 15) * 4;
    float4 ov = *(const float4*)&ot[orow * 68 + oc4];
    *(float4*)(outp + (long long)(bm + orow) * 1024 + g * 64 + oc4) = ov;
}

__global__ __launch_bounds__(256) void attn_out_kernel(
    const unsigned short* __restrict__ qk_pack,
    const _Float16* __restrict__ bias_gt, const _Float16* __restrict__ bias_ctx,
    const unsigned short* __restrict__ vt_pack, const float* __restrict__ b_conv,
    float* __restrict__ out_gt, float* __restrict__ out_ctx)
{
    __shared__ __align__(16) unsigned short wpack[16 * 1032];
    __shared__ float redA[64], redB[64];

    const int bx = blockIdx.x;
    if (bx < 512) {
        const int rb = bx & 31;
        attn_body<16>(bx >> 5, rb, qk_pack, /*pA=*/rb, /*pB0=*/32,
                      bias_gt, vt_pack, /*cc0=*/8, b_conv, out_gt,
                      wpack, redA, redB);
    } else {
        const int b2 = bx - 512;
        const int rb = b2 & 63;
        attn_body<8>(b2 >> 6, rb, qk_pack, /*pA=*/32 + rb, /*pB0=*/0,
                     bias_ctx, vt_pack, /*cc0=*/0, b_conv, out_ctx,
                     wpack, redA, redB);
    }
}

// ---------------------------------------------------------------------------
extern "C" void kernel_launch(void* const* d_in, const int* in_sizes, int n_in,
                              void* d_out, int out_size, void* d_ws, size_t ws_size,
                              hipStream_t stream)
{
    const float* feat     = (const float*)d_in[0];
    const float* ctx_feat = (const float*)d_in[1];
    const float* box      = (const float*)d_in[2];
    const float* ctx_box  = (const float*)d_in[3];
    const float* w_fc_gt  = (const float*)d_in[4];
    const float* b_fc_gt  = (const float*)d_in[5];
    const float* w_fc_ctx = (const float*)d_in[6];
    const float* b_fc_ctx = (const float*)d_in[7];
    const float* w_pos_gt = (const float*)d_in[8];
    const float* b_pos_gt = (const float*)d_in[9];
    const float* w_pos_ctx= (const float*)d_in[10];
    const float* b_pos_ctx= (const float*)d_in[11];
    const float* w_conv   = (const float*)d_in[12];
    const float* b_conv   = (const float*)d_in[13];

    float* ws = (float*)d_ws;
    unsigned short* in_bf   = (unsigned short*)ws;           // 1572864 s
    unsigned short* ctx_bf  = in_bf + 524288LL;
    unsigned short* qk_pack = in_bf + 1572864LL;             // 1572864 s
    _Float16* bias_gt  = (_Float16*)(ws + 1572864LL);        // 8388608 h
    _Float16* bias_ctx = (_Float16*)(ws + 5767168LL);        // 8388608 h
    unsigned short* wconv_bf = (unsigned short*)(ws + 9961472LL);   // 1048576 s
    unsigned short* vt_pack  = (unsigned short*)(ws + 10485760LL);  // 1572864 s
    unsigned short* wfcgt_bf = (unsigned short*)(ws + 11272192LL);  // 1048576 s
    unsigned short* wfcctx_bf= wfcgt_bf + 1048576LL;                // 1048576 s

    float* out_gt  = (float*)d_out;
    float* out_ctx = (float*)d_out + 524288LL;

    // 1) merged casts + position bias
    hipLaunchKernelGGL(prep_kernel, dim3(21504), dim3(256), 0, stream,
                       box, ctx_box, w_pos_gt, b_pos_gt, w_pos_ctx, b_pos_ctx,
                       bias_gt, bias_ctx,
                       feat, in_bf, 524288,
                       ctx_feat, ctx_bf, 1048576,
                       w_fc_gt, wfcgt_bf, 1048576,
                       w_fc_ctx, wfcctx_bf, 1048576,
                       w_conv, wconv_bf, 1048576);

    // 2) merged q/k projection + v-projection, fragment-packed output
    hipLaunchKernelGGL(projvt_kernel, dim3(24, 16, 2), dim3(256), 0, stream,
                       in_bf, wfcgt_bf, wfcctx_bf, b_fc_gt, b_fc_ctx, qk_pack,
                       wconv_bf, vt_pack);

    // 3) fused scores+softmax+output, both directions
    hipLaunchKernelGGL(attn_out_kernel, dim3(1536), dim3(256), 0, stream,
                       qk_pack, bias_gt, bias_ctx, vt_pack, b_conv, out_gt, out_ctx);
}

// Round 12
// 149.796 us; speedup vs baseline: 1.2026x; 1.0452x over previous
//
#include <hip/hip_runtime.h>
#include <math.h>

// M=512, N=1024, G=16, D=64, C=1024. All GEMM-shaped work on bf16 MFMA 16x16x32.
// pos_bias uses a bf16 hi/lo split MFMA (rounds 4/6: plain bf16 dot error
// ~2e-4 sign-flips entries in log-clip floor rows -> absmax 0.205).
//
// Round 12: prep pos branch restructured. r11 counter-model showed ~2600
// lane-ops/pair vs ~780 ideal: 4x-replicated per-pair scalar work (box loads,
// 2 IEEE fp32 divisions ~12 instr each, logs) + per-64-pair block overheads.
// Fixes: (a) phase-A computes each pos component ONCE (thread (pl,p)) into
// LDS; fragment lanes ds_read it. (b) v_rcp+mul instead of IEEE div.
// (c) 256 pairs/block: B-stage + B-fragment reads hoisted, barriers amortized.
//
// Pipeline (3 launches): prep (casts + pos_bias) -> projvt (packed) -> attn_out.
//
// qk_pack[g][p][part][lane][8shorts]: X[row][col], row=p*16+(lane&15),
// col=part*32+(lane>>4)*8+j (g-slice base g*64); p: q rows p=row>>4 (0..31),
// k rows 32+(row-512)>>4 (32..95). vt_pack[g][cc][p][part][lane][8]: p=o>>4.
//
// Workspace (float offsets), total 12,320,768 floats = 49.3 MB:
//   [0,1572864)        : shorts: in_bf (feat 524288 + ctx 1048576), qk_pack (1572864)
//   [1572864,5767168)  : bias_gt  fp16 (16,512,1024)
//   [5767168,9961472)  : bias_ctx fp16 (16,1024,512)
//   [9961472,10485760) : wconv_bf (1048576 s)
//   [10485760,11272192): vt_pack (1572864 s)
//   [11272192,12320768): wfcgt_bf + wfcctx_bf

typedef __attribute__((ext_vector_type(8))) short short8;   // 8 bf16 = 4 VGPRs
typedef __attribute__((ext_vector_type(4))) float floatx4;
typedef __attribute__((ext_vector_type(4))) _Float16 half4;
typedef __attribute__((ext_vector_type(4))) unsigned uint4v;

__device__ inline unsigned short f32_bf16_rne(float x) {
    union { float f; unsigned u; } v; v.f = x;
    unsigned u = v.u;
    return (unsigned short)((u + 0x7fffu + ((u >> 16) & 1u)) >> 16);
}

__device__ inline unsigned fbits(float x) {
    union { float f; unsigned u; } v; v.f = x; return v.u;
}
__device__ inline float bitsf(unsigned u) {
    union { unsigned u; float f; } v; v.u = u; return v.f;
}

__device__ __forceinline__ floatx4 mfma16(short8 a, short8 b, floatx4 c) {
    return __builtin_amdgcn_mfma_f32_16x16x32_bf16(a, b, c, 0, 0, 0);
}

// ---------------------------------------------------------------------------
// 64x64 tile NT bf16 GEMM core with FRAGMENT-PACKED output (r10, verified).
// ---------------------------------------------------------------------------
__device__ __forceinline__ void gemm_tile_pack(
    const unsigned short* __restrict__ Ab, int lda,
    const unsigned short* __restrict__ Bb, int ldb, int K,
    unsigned short* __restrict__ out_base,
    const float* __restrict__ biasvec,
    unsigned short* As, unsigned short* Bs)
{
    const int tid = threadIdx.x;
    const int lr = tid >> 3;          // 0..31 (8 lanes/row)
    const int lk = (tid & 7) * 8;     // 0..56
    const int lane = tid & 63;
    const int wave = tid >> 6;
    const int qr = (wave >> 1) * 32;
    const int qc = (wave & 1) * 32;
    const int m = lane & 15;
    const int quad = lane >> 4;

    const unsigned short* Ap  = Ab + (long long)lr * lda + lk;
    const unsigned short* Ap2 = Ap + 32LL * lda;
    const unsigned short* Bp  = Bb + (long long)lr * ldb + lk;
    const unsigned short* Bp2 = Bp + 32LL * ldb;
    unsigned short* AsW  = As + lr * 72 + lk;
    unsigned short* AsW2 = As + (lr + 32) * 72 + lk;
    unsigned short* BsW  = Bs + lr * 72 + lk;
    unsigned short* BsW2 = Bs + (lr + 32) * 72 + lk;
    const unsigned short* a0p = As + (qr + m) * 72 + quad * 8;
    const unsigned short* b0p = Bs + (qc + m) * 72 + quad * 8;

    floatx4 acc00 = {0.f,0.f,0.f,0.f}, acc01 = {0.f,0.f,0.f,0.f};
    floatx4 acc10 = {0.f,0.f,0.f,0.f}, acc11 = {0.f,0.f,0.f,0.f};

    int4 pa0 = *(const int4*)Ap;
    int4 pa1 = *(const int4*)Ap2;
    int4 pb0 = *(const int4*)Bp;
    int4 pb1 = *(const int4*)Bp2;
    int4 qa0 = *(const int4*)(Ap + 64);
    int4 qa1 = *(const int4*)(Ap2 + 64);
    int4 qb0 = *(const int4*)(Bp + 64);
    int4 qb1 = *(const int4*)(Bp2 + 64);

    for (int k0 = 0; ; ) {
        __syncthreads();
        *(int4*)AsW  = pa0;
        *(int4*)AsW2 = pa1;
        *(int4*)BsW  = pb0;
        *(int4*)BsW2 = pb1;
        __syncthreads();
        pa0 = qa0; pa1 = qa1; pb0 = qb0; pb1 = qb1;
        const int kf = k0 + 128;
        if (kf < K) {
            qa0 = *(const int4*)(Ap + kf);
            qa1 = *(const int4*)(Ap2 + kf);
            qb0 = *(const int4*)(Bp + kf);
            qb1 = *(const int4*)(Bp2 + kf);
        }
        #pragma unroll
        for (int kk = 0; kk < 64; kk += 32) {
            short8 a0 = *(const short8*)(a0p + kk);
            short8 a1 = *(const short8*)(a0p + 16 * 72 + kk);
            short8 b0 = *(const short8*)(b0p + kk);
            short8 b1 = *(const short8*)(b0p + 16 * 72 + kk);
            acc00 = mfma16(a0, b0, acc00);
            acc01 = mfma16(a0, b1, acc01);
            acc10 = mfma16(a1, b0, acc10);
            acc11 = mfma16(a1, b1, acc11);
        }
        k0 += 64;
        if (k0 >= K) break;
    }

    float bias0 = 0.f, bias1 = 0.f;
    if (biasvec) { bias0 = biasvec[qc + m]; bias1 = biasvec[qc + 16 + m]; }

    __syncthreads();
    const floatx4 accs[2][2] = { {acc00, acc01}, {acc10, acc11} };
    #pragma unroll
    for (int i = 0; i < 2; ++i)
        #pragma unroll
        for (int r = 0; r < 4; ++r) {
            const int lrow = qr + i * 16 + quad * 4 + r;
            #pragma unroll
            for (int j = 0; j < 2; ++j) {
                const int lcol = qc + j * 16 + m;
                float val = accs[i][j][r] + (j ? bias1 : bias0);
                As[lrow * 72 + lcol] = f32_bf16_rne(val);
            }
        }
    __syncthreads();
    #pragma unroll
    for (int h = 0; h < 2; ++h) {
        const int f = h * 2048 + tid * 8;
        const int lanep = (f >> 3) & 63;
        const int part = (f >> 9) & 1;
        const int ploc = f >> 10;
        const int row = ploc * 16 + (lanep & 15);
        const int col = part * 32 + ((lanep >> 4) << 3);
        short8 v8 = *(const short8*)&As[row * 72 + col];
        *(short8*)(out_base + f) = v8;
    }
}

// ---------------------------------------------------------------------------
__global__ __launch_bounds__(256) void projvt_kernel(
    const unsigned short* __restrict__ in_bf, const unsigned short* __restrict__ wgt,
    const unsigned short* __restrict__ wctx,
    const float* __restrict__ bgt, const float* __restrict__ bctx,
    unsigned short* __restrict__ qk_pack,
    const unsigned short* __restrict__ wconv, unsigned short* __restrict__ vt_pack)
{
    __shared__ __align__(16) unsigned short As[64 * 72];
    __shared__ __align__(16) unsigned short Bs[64 * 72];
    if (blockIdx.z == 0) {
        const int bm = blockIdx.x * 64;
        const int g = blockIdx.y;
        const unsigned short* B = (bm < 512) ? wgt : wctx;
        const float* bias = (bm < 512) ? bgt : bctx;
        gemm_tile_pack(in_bf + (long long)bm * 1024, 1024,
                       B + (long long)g * 65536, 1024, 1024,
                       qk_pack + ((long long)g * 96 + blockIdx.x * 4) * 1024,
                       bias + g * 64, As, Bs);
    } else {
        const int cc = blockIdx.x;       // 0..23
        const int g = blockIdx.y;
        gemm_tile_pack(wconv + (long long)g * 65536, 1024,
                       in_bf + (long long)cc * 65536, 1024, 1024,
                       vt_pack + ((long long)g * 24 + cc) * 4096,
                       nullptr, As, Bs);
    }
}

// ---------------------------------------------------------------------------
// Merged prep: blocks [0,4096) = pos_bias (256 pairs/block), [4096,9216) =
// fp32->bf16 casts.
// pos_bias per 64-pair chunk: phase A computes each pair's 4 pos components
// once (thread (pl,p), v_rcp fast division) -> posL; phase B builds hi/lo
// A-fragments in registers from posL, 6x MFMA vs hoisted B-fragments, log ->
// stg -> coalesced fp16 store.
// ---------------------------------------------------------------------------
__global__ __launch_bounds__(256) void prep_kernel(
    const float* __restrict__ box, const float* __restrict__ ctx_box,
    const float* __restrict__ w_gt, const float* __restrict__ b_gt,
    const float* __restrict__ w_ctx, const float* __restrict__ b_ctx,
    _Float16* __restrict__ bias_gt, _Float16* __restrict__ bias_ctx,
    const float* s0, unsigned short* d0, int n0,
    const float* s1, unsigned short* d1, int n1,
    const float* s2, unsigned short* d2, int n2,
    const float* s3, unsigned short* d3, int n3,
    const float* s4, unsigned short* d4, int n4)
{
    const int bx = blockIdx.x;
    if (bx >= 4096) {                    // -------- cast branch
        const int bc = bx - 4096;
        const int which = bc >> 10;
        const int xb = bc & 1023;
        const float* s; unsigned short* d; int n;
        switch (which) {
            case 0: s = s0; d = d0; n = n0; break;
            case 1: s = s1; d = d1; n = n1; break;
            case 2: s = s2; d = d2; n = n2; break;
            case 3: s = s3; d = d3; n = n3; break;
            default: s = s4; d = d4; n = n4; break;
        }
        int idx = (xb * 256 + threadIdx.x) * 4;
        if (idx < n) {
            float4 v = *(const float4*)(s + idx);
            ushort4 o;
            o.x = f32_bf16_rne(v.x); o.y = f32_bf16_rne(v.y);
            o.z = f32_bf16_rne(v.z); o.w = f32_bf16_rne(v.w);
            *(ushort4*)(d + idx) = o;
        }
        return;
    }

    // -------- pos_bias branch: 256 pairs per block
    const bool first = (bx < 2048);
    const long long blk = first ? bx : (bx - 2048);
    const float* boxA = first ? box : ctx_box;
    const float* boxB = first ? ctx_box : box;
    const float* w_pos = first ? w_gt : w_ctx;
    const float* b_pos = first ? b_gt : b_ctx;
    _Float16* out = first ? bias_gt : bias_ctx;
    const int shift = first ? 10 : 9;

    __shared__ __align__(16) unsigned short BsH[16 * 72];
    __shared__ __align__(16) unsigned short BsL[16 * 72];
    __shared__ float posL[4 * 68];       // [p][pair_local], stride 68
    __shared__ _Float16 stg[16 * 68];

    const int tid = threadIdx.x;

    {   // stage B: w_pos (16x64 fp32) -> bf16 hi + lo (trunc split, packed)
        const int g = tid >> 4;
        const int d = (tid & 15) * 4;
        float4 wv = *(const float4*)(w_pos + g * 64 + d);
        unsigned u0 = fbits(wv.x), u1 = fbits(wv.y);
        unsigned u2 = fbits(wv.z), u3 = fbits(wv.w);
        unsigned r0 = fbits(wv.x - bitsf(u0 & 0xFFFF0000u));
        unsigned r1 = fbits(wv.y - bitsf(u1 & 0xFFFF0000u));
        unsigned r2 = fbits(wv.z - bitsf(u2 & 0xFFFF0000u));
        unsigned r3 = fbits(wv.w - bitsf(u3 & 0xFFFF0000u));
        uint2 hv, lv;
        hv.x = (u0 >> 16) | (u1 & 0xFFFF0000u);
        hv.y = (u2 >> 16) | (u3 & 0xFFFF0000u);
        lv.x = (r0 >> 16) | (r1 & 0xFFFF0000u);
        lv.y = (r2 >> 16) | (r3 & 0xFFFF0000u);
        *(uint2*)&BsH[g * 72 + d] = hv;
        *(uint2*)&BsL[g * 72 + d] = lv;
    }
    __syncthreads();

    const int lane = tid & 63;
    const int w = tid >> 6;
    const int m = lane & 15;
    const int quad = lane >> 4;
    const bool qlow = (quad < 2);
    const float phase = (quad & 1) ? 1.57079632679f : 0.0f;  // cos(t)=sin(t+pi/2)
    const float bpv = b_pos[m];

    // hoist B-fragments (weights) out of the chunk loop
    const unsigned short* bpH = &BsH[m * 72 + quad * 8];
    const unsigned short* bpL = &BsL[m * 72 + quad * 8];
    short8 bH0 = *(const short8*)bpH;
    short8 bH1 = *(const short8*)(bpH + 32);
    short8 bL0 = *(const short8*)bpL;
    short8 bL1 = *(const short8*)(bpL + 32);

    const float w100[8] = {100.f, 42.169650342f, 17.782794100f, 7.498942093f,
                           3.162277660f, 1.333521432f, 0.562341325f, 0.237137371f};
    const long long pbase = blk * 256;

    for (int it = 0; it < 4; ++it) {
        const long long pb = pbase + it * 64;

        // ---- phase A: each pos component computed once (thread (pl, p))
        {
            const int pl = tid & 63;
            const int p = tid >> 6;      // wave-uniform
            const long long pair = pb + pl;
            const int i = (int)(pair >> shift);
            const int j = (int)(pair & ((1 << shift) - 1));
            float4 ba = *(const float4*)(boxA + i * 4);
            float4 bb = *(const float4*)(boxB + j * 4);
            float posv;
            if (p == 0) {
                float r = __builtin_amdgcn_rcpf(ba.z - ba.x + 1.f);
                posv = __logf(fmaxf(fabsf((0.5f*(ba.x+ba.z) - 0.5f*(bb.x+bb.z)) * r), 1e-3f));
            } else if (p == 1) {
                float r = __builtin_amdgcn_rcpf(ba.w - ba.y + 1.f);
                posv = __logf(fmaxf(fabsf((0.5f*(ba.y+ba.w) - 0.5f*(bb.y+bb.w)) * r), 1e-3f));
            } else if (p == 2) {
                float r = __builtin_amdgcn_rcpf(ba.z - ba.x + 1.f);
                posv = __logf((bb.z - bb.x + 1.f) * r);
            } else {
                float r = __builtin_amdgcn_rcpf(ba.w - ba.y + 1.f);
                posv = __logf((bb.w - bb.y + 1.f) * r);
            }
            posL[p * 68 + pl] = posv;
        }
        __syncthreads();

        // ---- phase B: A-fragments in registers from posL
        const int plB = w * 16 + m;
        const float pos_lo = posL[(qlow ? 0 : 1) * 68 + plB];
        const float pos_hi = posL[(qlow ? 2 : 3) * 68 + plB];

        unsigned hp0[4], lp0[4], hp1[4], lp1[4];
        #pragma unroll
        for (int fi = 0; fi < 4; ++fi) {
            float x0 = fmaxf(__sinf(fmaf(w100[2*fi],     pos_lo, phase)), 0.f);
            float x1 = fmaxf(__sinf(fmaf(w100[2*fi + 1], pos_lo, phase)), 0.f);
            unsigned u0 = fbits(x0), u1 = fbits(x1);
            unsigned r0 = fbits(x0 - bitsf(u0 & 0xFFFF0000u));
            unsigned r1 = fbits(x1 - bitsf(u1 & 0xFFFF0000u));
            hp0[fi] = (u0 >> 16) | (u1 & 0xFFFF0000u);
            lp0[fi] = (r0 >> 16) | (r1 & 0xFFFF0000u);
            float y0 = fmaxf(__sinf(fmaf(w100[2*fi],     pos_hi, phase)), 0.f);
            float y1 = fmaxf(__sinf(fmaf(w100[2*fi + 1], pos_hi, phase)), 0.f);
            unsigned v0 = fbits(y0), v1 = fbits(y1);
            unsigned s0r = fbits(y0 - bitsf(v0 & 0xFFFF0000u));
            unsigned s1r = fbits(y1 - bitsf(v1 & 0xFFFF0000u));
            hp1[fi] = (v0 >> 16) | (v1 & 0xFFFF0000u);
            lp1[fi] = (s0r >> 16) | (s1r & 0xFFFF0000u);
        }
        union { uint4v u; short8 s; } cH0, cL0, cH1, cL1;
        cH0.u = (uint4v){hp0[0], hp0[1], hp0[2], hp0[3]};
        cL0.u = (uint4v){lp0[0], lp0[1], lp0[2], lp0[3]};
        cH1.u = (uint4v){hp1[0], hp1[1], hp1[2], hp1[3]};
        cL1.u = (uint4v){lp1[0], lp1[1], lp1[2], lp1[3]};

        floatx4 acc = {0.f, 0.f, 0.f, 0.f};
        acc = mfma16(cH0.s, bH0, acc);
        acc = mfma16(cH1.s, bH1, acc);
        acc = mfma16(cH0.s, bL0, acc);
        acc = mfma16(cH1.s, bL1, acc);
        acc = mfma16(cL0.s, bH0, acc);
        acc = mfma16(cL1.s, bH1, acc);

        // C: row = pair-local w*16 + quad*4 + r, col = group m
        #pragma unroll
        for (int r = 0; r < 4; ++r)
            stg[m * 68 + w * 16 + quad * 4 + r] =
                (_Float16)__logf(fmaxf(acc[r] + bpv, 1e-6f));
        __syncthreads();   // stg ready; also posL reads of this chunk complete

        const int g2 = tid >> 4, c16 = tid & 15;
        *(half4*)(out + (long long)g2 * 524288 + pb + c16 * 4) =
            *(const half4*)&stg[g2 * 68 + c16 * 4];
        // next phase A writes posL (not stg) -> safe; next stg write is after
        // the next barrier -> store reads above are protected.
    }
}

// ---------------------------------------------------------------------------
// Fused scores + bias + softmax + output GEMM (r10, verified).
// ---------------------------------------------------------------------------
template <int NC>
__device__ __forceinline__ void attn_body(
    int g, int bx,
    const unsigned short* __restrict__ qk, int pA, int pB0,
    const _Float16* __restrict__ bias,
    const unsigned short* __restrict__ vt, int cc0,
    const float* __restrict__ b_conv, float* __restrict__ outp,
    unsigned short* wpack, float* redA, float* redB)
{
    constexpr int NCOL = NC * 64;
    constexpr int WS = NCOL + 8;
    constexpr int SHIFT = (NC == 16) ? 10 : 9;

    const int bm = bx * 16;
    const int tid = threadIdx.x;
    const int lane = tid & 63;
    const int w = tid >> 6;
    const int m = lane & 15;
    const int quad = lane >> 4;

    _Float16* bb = (_Float16*)wpack;
    {
        const _Float16* bsrc = bias + (long long)g * 524288 + (long long)bm * NCOL;
        #pragma unroll
        for (int i = 0; i < (16 * NCOL) / (256 * 8); ++i) {
            const int idx = (i * 256 + tid) * 8;
            const int row = idx >> SHIFT;
            const int col = idx & (NCOL - 1);
            *(int4*)(bb + row * WS + col) = *(const int4*)(bsrc + idx);
        }
    }

    const unsigned short* abase = qk + ((long long)(g * 96 + pA)) * 1024;
    short8 aq0 = *(const short8*)(abase + lane * 8);
    short8 aq1 = *(const short8*)(abase + 512 + lane * 8);

    const unsigned short* bptr = qk + ((long long)(g * 96 + pB0 + w)) * 1024 + lane * 8;
    short8 B0[2], B1[2];
    B0[0] = *(const short8*)bptr;
    B1[0] = *(const short8*)(bptr + 512);
    B0[1] = *(const short8*)(bptr + 4096);
    B1[1] = *(const short8*)(bptr + 4096 + 512);

    __syncthreads();   // bias staged

    const _Float16* brow = bb + (quad * 4) * WS + w * 16 + m;

    float v[NC][4];
    #pragma unroll
    for (int c = 0; c < NC; ++c) {
        float bv[4];
        #pragma unroll
        for (int r = 0; r < 4; ++r)
            bv[r] = (float)brow[r * WS + c * 64];
        floatx4 acc = {0.f, 0.f, 0.f, 0.f};
        acc = mfma16(aq0, B0[c & 1], acc);
        acc = mfma16(aq1, B1[c & 1], acc);
        if (c + 2 < NC) {
            const unsigned short* nb = bptr + (long long)(c + 2) * 4096;
            B0[c & 1] = *(const short8*)nb;
            B1[c & 1] = *(const short8*)(nb + 512);
        }
        #pragma unroll
        for (int r = 0; r < 4; ++r)
            v[c][r] = fmaf(0.125f, acc[r], bv[r]);
    }

    const unsigned short* vptr = vt + ((long long)(g * 24 + cc0)) * 4096
                               + w * 1024 + lane * 8;
    short8 V0[2], V1[2];
    V0[0] = *(const short8*)vptr;
    V1[0] = *(const short8*)(vptr + 512);
    V0[1] = *(const short8*)(vptr + 4096);
    V1[1] = *(const short8*)(vptr + 4096 + 512);

    float rmax[4];
    #pragma unroll
    for (int r = 0; r < 4; ++r) {
        float mx = v[0][r];
        #pragma unroll
        for (int c = 1; c < NC; ++c) mx = fmaxf(mx, v[c][r]);
        #pragma unroll
        for (int off = 1; off < 16; off <<= 1)
            mx = fmaxf(mx, __shfl_xor(mx, off, 64));
        rmax[r] = mx;
    }
    if (m == 0) {
        #pragma unroll
        for (int r = 0; r < 4; ++r) redA[w * 16 + quad * 4 + r] = rmax[r];
    }
    __syncthreads();
    #pragma unroll
    for (int r = 0; r < 4; ++r)
        rmax[r] = fmaxf(fmaxf(redA[quad*4+r], redA[16 + quad*4+r]),
                        fmaxf(redA[32 + quad*4+r], redA[48 + quad*4+r]));

    float rsum[4] = {0.f, 0.f, 0.f, 0.f};
    #pragma unroll
    for (int c = 0; c < NC; ++c)
        #pragma unroll
        for (int r = 0; r < 4; ++r) {
            v[c][r] = __expf(v[c][r] - rmax[r]);
            rsum[r] += v[c][r];
        }
    #pragma unroll
    for (int r = 0; r < 4; ++r)
        #pragma unroll
        for (int off = 1; off < 16; off <<= 1)
            rsum[r] += __shfl_xor(rsum[r], off, 64);
    if (m == 0) {
        #pragma unroll
        for (int r = 0; r < 4; ++r) redB[w * 16 + quad * 4 + r] = rsum[r];
    }
    __syncthreads();   // all bias reads complete before wpack overwrite
    float rinv[4];
    #pragma unroll
    for (int r = 0; r < 4; ++r)
        rinv[r] = 1.f / (redB[quad*4+r] + redB[16 + quad*4+r] +
                         redB[32 + quad*4+r] + redB[48 + quad*4+r]);

    #pragma unroll
    for (int c = 0; c < NC; ++c)
        #pragma unroll
        for (int r = 0; r < 4; ++r)
            wpack[(quad * 4 + r) * WS + c * 64 + w * 16 + m] =
                f32_bf16_rne(v[c][r] * rinv[r]);

    __syncthreads();   // wpack visible

    floatx4 oacc = {0.f, 0.f, 0.f, 0.f};
    const unsigned short* awp = wpack + m * WS + quad * 8;
    #pragma unroll
    for (int kc = 0; kc < NC; ++kc) {
        short8 a0 = *(const short8*)(awp + kc * 64);
        short8 a1 = *(const short8*)(awp + kc * 64 + 32);
        oacc = mfma16(a0, V0[kc & 1], oacc);
        oacc = mfma16(a1, V1[kc & 1], oacc);
        if (kc + 2 < NC) {
            const unsigned short* nv = vptr + (long long)(kc + 2) * 4096;
            V0[kc & 1] = *(const short8*)nv;
            V1[kc & 1] = *(const short8*)(nv + 512);
        }
    }

    const int o = w * 16 + m;
    const float bc = b_conv[g * 64 + o];
    __syncthreads();   // wpack weight reads done
    float* ot = (float*)wpack;         // 16 x 68 floats
    #pragma unroll
    for (int r = 0; r < 4; ++r)
        ot[(quad * 4 + r) * 68 + o] = oacc[r] + bc;
    __syncthreads();
    const int orow = tid >> 4, oc4 = (tid & 15) * 4;
    float4 ov = *(const float4*)&ot[orow * 68 + oc4];
    *(float4*)(outp + (long long)(bm + orow) * 1024 + g * 64 + oc4) = ov;
}

__global__ __launch_bounds__(256) void attn_out_kernel(
    const unsigned short* __restrict__ qk_pack,
    const _Float16* __restrict__ bias_gt, const _Float16* __restrict__ bias_ctx,
    const unsigned short* __restrict__ vt_pack, const float* __restrict__ b_conv,
    float* __restrict__ out_gt, float* __restrict__ out_ctx)
{
    __shared__ __align__(16) unsigned short wpack[16 * 1032];
    __shared__ float redA[64], redB[64];

    const int bx = blockIdx.x;
    if (bx < 512) {
        const int rb = bx & 31;
        attn_body<16>(bx >> 5, rb, qk_pack, /*pA=*/rb, /*pB0=*/32,
                      bias_gt, vt_pack, /*cc0=*/8, b_conv, out_gt,
                      wpack, redA, redB);
    } else {
        const int b2 = bx - 512;
        const int rb = b2 & 63;
        attn_body<8>(b2 >> 6, rb, qk_pack, /*pA=*/32 + rb, /*pB0=*/0,
                     bias_ctx, vt_pack, /*cc0=*/0, b_conv, out_ctx,
                     wpack, redA, redB);
    }
}

// ---------------------------------------------------------------------------
extern "C" void kernel_launch(void* const* d_in, const int* in_sizes, int n_in,
                              void* d_out, int out_size, void* d_ws, size_t ws_size,
                              hipStream_t stream)
{
    const float* feat     = (const float*)d_in[0];
    const float* ctx_feat = (const float*)d_in[1];
    const float* box      = (const float*)d_in[2];
    const float* ctx_box  = (const float*)d_in[3];
    const float* w_fc_gt  = (const float*)d_in[4];
    const float* b_fc_gt  = (const float*)d_in[5];
    const float* w_fc_ctx = (const float*)d_in[6];
    const float* b_fc_ctx = (const float*)d_in[7];
    const float* w_pos_gt = (const float*)d_in[8];
    const float* b_pos_gt = (const float*)d_in[9];
    const float* w_pos_ctx= (const float*)d_in[10];
    const float* b_pos_ctx= (const float*)d_in[11];
    const float* w_conv   = (const float*)d_in[12];
    const float* b_conv   = (const float*)d_in[13];

    float* ws = (float*)d_ws;
    unsigned short* in_bf   = (unsigned short*)ws;           // 1572864 s
    unsigned short* ctx_bf  = in_bf + 524288LL;
    unsigned short* qk_pack = in_bf + 1572864LL;             // 1572864 s
    _Float16* bias_gt  = (_Float16*)(ws + 1572864LL);        // 8388608 h
    _Float16* bias_ctx = (_Float16*)(ws + 5767168LL);        // 8388608 h
    unsigned short* wconv_bf = (unsigned short*)(ws + 9961472LL);   // 1048576 s
    unsigned short* vt_pack  = (unsigned short*)(ws + 10485760LL);  // 1572864 s
    unsigned short* wfcgt_bf = (unsigned short*)(ws + 11272192LL);  // 1048576 s
    unsigned short* wfcctx_bf= wfcgt_bf + 1048576LL;                // 1048576 s

    float* out_gt  = (float*)d_out;
    float* out_ctx = (float*)d_out + 524288LL;

    // 1) merged casts + position bias (pos: 4096 blocks x 256 pairs; cast: 5120)
    hipLaunchKernelGGL(prep_kernel, dim3(9216), dim3(256), 0, stream,
                       box, ctx_box, w_pos_gt, b_pos_gt, w_pos_ctx, b_pos_ctx,
                       bias_gt, bias_ctx,
                       feat, in_bf, 524288,
                       ctx_feat, ctx_bf, 1048576,
                       w_fc_gt, wfcgt_bf, 1048576,
                       w_fc_ctx, wfcctx_bf, 1048576,
                       w_conv, wconv_bf, 1048576);

    // 2) merged q/k projection + v-projection, fragment-packed output
    hipLaunchKernelGGL(projvt_kernel, dim3(24, 16, 2), dim3(256), 0, stream,
                       in_bf, wfcgt_bf, wfcctx_bf, b_fc_gt, b_fc_ctx, qk_pack,
                       wconv_bf, vt_pack);

    // 3) fused scores+softmax+output, both directions
    hipLaunchKernelGGL(attn_out_kernel, dim3(1536), dim3(256), 0, stream,
                       qk_pack, bias_gt, bias_ctx, vt_pack, b_conv, out_gt, out_ctx);
}